// Round 1
// baseline (343.748 us; speedup 1.0000x reference)
//
#include <hip/hip_runtime.h>

#define B_ 4
#define S_ 2048
#define H_ 1024
#define NH_ 16
#define HD_ 64
#define SCALE_ 0.125f

typedef __attribute__((ext_vector_type(8))) short bf16x8;
typedef __attribute__((ext_vector_type(4))) float f32x4;

__device__ __forceinline__ unsigned short f2bf(float f) {
    unsigned u = __float_as_uint(f);
    unsigned r = (u + 0x7FFFu + ((u >> 16) & 1u)) >> 16;
    return (unsigned short)r;
}

// ---------------- cast fp32 -> bf16 (vectorized) ----------------
__global__ __launch_bounds__(256) void cast_f32_bf16(const float* __restrict__ in,
                                                     unsigned short* __restrict__ out, int n4) {
    int i = blockIdx.x * 256 + threadIdx.x;
    if (i < n4) {
        float4 v = reinterpret_cast<const float4*>(in)[i];
        ushort4 o;
        o.x = f2bf(v.x); o.y = f2bf(v.y); o.z = f2bf(v.z); o.w = f2bf(v.w);
        reinterpret_cast<ushort4*>(out)[i] = o;
    }
}

// ---------------- staging: 128 rows x 128 bytes, XOR slot-swizzled ----------------
// LDS(r, slot) holds global(r, slot ^ (r&7)); reader XORs the same way (involution).
__device__ __forceinline__ void stage128_swz(const char* g, int gstride, char* lds, int tid) {
    int wave = tid >> 6, lane = tid & 63;
#pragma unroll
    for (int j = 0; j < 4; ++j) {
        int o = ((wave * 4 + j) * 64 + lane) * 16;
        int r = o >> 7;
        int slot = (o >> 4) & 7;
        const char* src = g + (size_t)r * gstride + ((slot ^ (r & 7)) << 4);
        __builtin_amdgcn_global_load_lds((const __attribute__((address_space(1))) void*)src,
                                         (__attribute__((address_space(3))) void*)(lds + (wave * 4 + j) * 1024),
                                         16, 0, 0);
    }
}

__device__ __forceinline__ bf16x8 frag_swz(const char* lds, int row, int slot) {
    return *reinterpret_cast<const bf16x8*>(lds + row * 128 + (((slot) ^ (row & 7)) << 4));
}

// ---------------- fused QKV projection GEMM: C[M,N] = A[M,K] * W[N,K]^T ----------------
__global__ __launch_bounds__(256) void gemm_qkv(const unsigned short* __restrict__ xb,
                                                const unsigned short* __restrict__ Wq,
                                                const unsigned short* __restrict__ Wk,
                                                const unsigned short* __restrict__ Wv,
                                                unsigned short* __restrict__ Qo,
                                                unsigned short* __restrict__ Ko,
                                                unsigned short* __restrict__ Vo) {
    __shared__ __align__(16) char As[128 * 128];
    __shared__ __align__(16) char Bs[128 * 128];
    int tid = threadIdx.x, lane = tid & 63, wave = tid >> 6;
    int wr = wave >> 1, wc = wave & 1;
    int brow = blockIdx.x * 128;
    int mat = blockIdx.y >> 3;
    int bcol = (blockIdx.y & 7) * 128;
    const unsigned short* W = mat == 0 ? Wq : (mat == 1 ? Wk : Wv);
    unsigned short* O = mat == 0 ? Qo : (mat == 1 ? Ko : Vo);
    f32x4 acc[4][4] = {};
    const char* ga = (const char*)(xb + (size_t)brow * H_);
    const char* gb = (const char*)(W + (size_t)bcol * H_);
    int ro = lane & 15, kg = lane >> 4;
    for (int kt = 0; kt < H_ / 64; ++kt) {
        stage128_swz(ga + kt * 128, H_ * 2, As, tid);
        stage128_swz(gb + kt * 128, H_ * 2, Bs, tid);
        __syncthreads();
#pragma unroll
        for (int kk = 0; kk < 2; ++kk) {
            bf16x8 af[4], bfr[4];
#pragma unroll
            for (int m = 0; m < 4; ++m) af[m] = frag_swz(As, wr * 64 + m * 16 + ro, kk * 4 + kg);
#pragma unroll
            for (int n = 0; n < 4; ++n) bfr[n] = frag_swz(Bs, wc * 64 + n * 16 + ro, kk * 4 + kg);
#pragma unroll
            for (int m = 0; m < 4; ++m)
#pragma unroll
                for (int n = 0; n < 4; ++n)
                    acc[m][n] = __builtin_amdgcn_mfma_f32_16x16x32_bf16(af[m], bfr[n], acc[m][n], 0, 0, 0);
        }
        __syncthreads();
    }
#pragma unroll
    for (int m = 0; m < 4; ++m)
#pragma unroll
        for (int n = 0; n < 4; ++n)
#pragma unroll
            for (int i = 0; i < 4; ++i) {
                int row = brow + wr * 64 + m * 16 + kg * 4 + i;
                int col = bcol + wc * 64 + n * 16 + ro;
                O[(size_t)row * H_ + col] = f2bf(acc[m][n][i]);
            }
}

// ---------------- output projection GEMM + bias, fp32 out ----------------
__global__ __launch_bounds__(256) void gemm_out(const unsigned short* __restrict__ Ab,
                                                const unsigned short* __restrict__ Wo,
                                                const float* __restrict__ bo,
                                                float* __restrict__ out) {
    __shared__ __align__(16) char As[128 * 128];
    __shared__ __align__(16) char Bs[128 * 128];
    int tid = threadIdx.x, lane = tid & 63, wave = tid >> 6;
    int wr = wave >> 1, wc = wave & 1;
    int brow = blockIdx.x * 128;
    int bcol = blockIdx.y * 128;
    f32x4 acc[4][4] = {};
    const char* ga = (const char*)(Ab + (size_t)brow * H_);
    const char* gb = (const char*)(Wo + (size_t)bcol * H_);
    int ro = lane & 15, kg = lane >> 4;
    for (int kt = 0; kt < H_ / 64; ++kt) {
        stage128_swz(ga + kt * 128, H_ * 2, As, tid);
        stage128_swz(gb + kt * 128, H_ * 2, Bs, tid);
        __syncthreads();
#pragma unroll
        for (int kk = 0; kk < 2; ++kk) {
            bf16x8 af[4], bfr[4];
#pragma unroll
            for (int m = 0; m < 4; ++m) af[m] = frag_swz(As, wr * 64 + m * 16 + ro, kk * 4 + kg);
#pragma unroll
            for (int n = 0; n < 4; ++n) bfr[n] = frag_swz(Bs, wc * 64 + n * 16 + ro, kk * 4 + kg);
#pragma unroll
            for (int m = 0; m < 4; ++m)
#pragma unroll
                for (int n = 0; n < 4; ++n)
                    acc[m][n] = __builtin_amdgcn_mfma_f32_16x16x32_bf16(af[m], bfr[n], acc[m][n], 0, 0, 0);
        }
        __syncthreads();
    }
#pragma unroll
    for (int n = 0; n < 4; ++n) {
        int col = bcol + wc * 64 + n * 16 + ro;
        float bn = bo[col];
#pragma unroll
        for (int m = 0; m < 4; ++m)
#pragma unroll
            for (int i = 0; i < 4; ++i) {
                int row = brow + wr * 64 + m * 16 + kg * 4 + i;
                out[(size_t)row * H_ + col] = acc[m][n][i] + bn;
            }
    }
}

// ---------------- flash attention (causal + padding mask) ----------------
// grid: (B*NH, S/128). 4 waves x 32 q-rows. Q in regs; K swizzled LDS; V^T padded LDS.
__global__ __launch_bounds__(256) void attn(const unsigned short* __restrict__ Q,
                                            const unsigned short* __restrict__ K,
                                            const unsigned short* __restrict__ V,
                                            const int* __restrict__ amask,
                                            unsigned short* __restrict__ Ab) {
    __shared__ __align__(16) char Ksm[128 * 128];
    __shared__ __align__(16) unsigned short Vt[HD_][136];
    __shared__ __align__(16) unsigned short Psm[4][32][136];
    __shared__ float mbias[128];
    int tid = threadIdx.x, lane = tid & 63, wave = tid >> 6;
    int bh = blockIdx.x;
    int b = bh >> 4, h = bh & 15;
    int qb = blockIdx.y;
    int brow = qb * 128;
    const unsigned short* Qg = Q + ((size_t)b * S_ + brow) * H_ + h * HD_;
    const unsigned short* Kg = K + (size_t)b * S_ * H_ + h * HD_;
    const unsigned short* Vg = V + (size_t)b * S_ * H_ + h * HD_;
    int ro = lane & 15, kg = lane >> 4;

    bf16x8 qf[2][2];
#pragma unroll
    for (int m = 0; m < 2; ++m)
#pragma unroll
        for (int kk = 0; kk < 2; ++kk)
            qf[m][kk] = *reinterpret_cast<const bf16x8*>(
                Qg + (size_t)(wave * 32 + m * 16 + ro) * H_ + kk * 32 + kg * 8);

    f32x4 oacc[2][4] = {};
    float mrun[2][4], lrun[2][4];
#pragma unroll
    for (int m = 0; m < 2; ++m)
#pragma unroll
        for (int i = 0; i < 4; ++i) { mrun[m][i] = -__builtin_inff(); lrun[m][i] = 0.f; }

    int ntile = qb + 1;
    for (int t = 0; t < ntile; ++t) {
        int kv0 = t * 128;
        stage128_swz((const char*)(Kg + (size_t)kv0 * H_), H_ * 2, Ksm, tid);
        // V transpose staging: read vec8 rows, scatter into Vt[d][kv] (stride 272B)
#pragma unroll
        for (int c = 0; c < 4; ++c) {
            int cid = c * 256 + tid;
            int r = cid >> 3, d0 = (cid & 7) * 8;
            bf16x8 vv = *reinterpret_cast<const bf16x8*>(Vg + (size_t)(kv0 + r) * H_ + d0);
#pragma unroll
            for (int j = 0; j < 8; ++j) Vt[d0 + j][r] = (unsigned short)vv[j];
        }
        if (tid < 128) mbias[tid] = (amask[b * S_ + kv0 + tid] == 0) ? -1e9f : 0.f;
        __syncthreads();

        // S = Q K^T
        f32x4 sa[2][8] = {};
#pragma unroll
        for (int kk = 0; kk < 2; ++kk) {
            bf16x8 kf[8];
#pragma unroll
            for (int n = 0; n < 8; ++n) kf[n] = frag_swz(Ksm, n * 16 + ro, kk * 4 + kg);
#pragma unroll
            for (int m = 0; m < 2; ++m)
#pragma unroll
                for (int n = 0; n < 8; ++n)
                    sa[m][n] = __builtin_amdgcn_mfma_f32_16x16x32_bf16(qf[m][kk], kf[n], sa[m][n], 0, 0, 0);
        }

        bool diag = (t == qb);
#pragma unroll
        for (int m = 0; m < 2; ++m) {
            int qrow_base = brow + wave * 32 + m * 16 + kg * 4;
            float mx[4] = {-__builtin_inff(), -__builtin_inff(), -__builtin_inff(), -__builtin_inff()};
#pragma unroll
            for (int n = 0; n < 8; ++n) {
                int col = kv0 + n * 16 + ro;
                float mb = mbias[n * 16 + ro];
#pragma unroll
                for (int i = 0; i < 4; ++i) {
                    float s = sa[m][n][i] * SCALE_;
                    if (mb < 0.f) s = -1e9f;
                    if (diag && col > qrow_base + i) s = -1e9f;
                    sa[m][n][i] = s;
                    mx[i] = fmaxf(mx[i], s);
                }
            }
            float mnew[4], fsc[4], rs[4];
#pragma unroll
            for (int i = 0; i < 4; ++i) {
                mx[i] = fmaxf(mx[i], __shfl_xor(mx[i], 1));
                mx[i] = fmaxf(mx[i], __shfl_xor(mx[i], 2));
                mx[i] = fmaxf(mx[i], __shfl_xor(mx[i], 4));
                mx[i] = fmaxf(mx[i], __shfl_xor(mx[i], 8));
                mnew[i] = fmaxf(mrun[m][i], mx[i]);
                fsc[i] = __expf(mrun[m][i] - mnew[i]);
                mrun[m][i] = mnew[i];
                rs[i] = 0.f;
            }
#pragma unroll
            for (int n = 0; n < 8; ++n)
#pragma unroll
                for (int i = 0; i < 4; ++i) {
                    float p = __expf(sa[m][n][i] - mnew[i]);
                    rs[i] += p;
                    Psm[wave][m * 16 + kg * 4 + i][n * 16 + ro] = f2bf(p);
                }
#pragma unroll
            for (int i = 0; i < 4; ++i) {
                rs[i] += __shfl_xor(rs[i], 1);
                rs[i] += __shfl_xor(rs[i], 2);
                rs[i] += __shfl_xor(rs[i], 4);
                rs[i] += __shfl_xor(rs[i], 8);
                lrun[m][i] = lrun[m][i] * fsc[i] + rs[i];
            }
#pragma unroll
            for (int n = 0; n < 4; ++n)
#pragma unroll
                for (int i = 0; i < 4; ++i) oacc[m][n][i] *= fsc[i];
        }

        // O += P V
#pragma unroll
        for (int ks = 0; ks < 4; ++ks) {
            bf16x8 pa[2], vb[4];
#pragma unroll
            for (int m = 0; m < 2; ++m)
                pa[m] = *reinterpret_cast<const bf16x8*>(&Psm[wave][m * 16 + ro][ks * 32 + kg * 8]);
#pragma unroll
            for (int n = 0; n < 4; ++n)
                vb[n] = *reinterpret_cast<const bf16x8*>(&Vt[n * 16 + ro][ks * 32 + kg * 8]);
#pragma unroll
            for (int m = 0; m < 2; ++m)
#pragma unroll
                for (int n = 0; n < 4; ++n)
                    oacc[m][n] = __builtin_amdgcn_mfma_f32_16x16x32_bf16(pa[m], vb[n], oacc[m][n], 0, 0, 0);
        }
        __syncthreads();
    }

#pragma unroll
    for (int m = 0; m < 2; ++m)
#pragma unroll
        for (int n = 0; n < 4; ++n)
#pragma unroll
            for (int i = 0; i < 4; ++i) {
                float v = oacc[m][n][i] / lrun[m][i];
                size_t row = (size_t)b * S_ + brow + wave * 32 + m * 16 + kg * 4 + i;
                Ab[row * H_ + h * HD_ + n * 16 + ro] = f2bf(v);
            }
}

extern "C" void kernel_launch(void* const* d_in, const int* in_sizes, int n_in,
                              void* d_out, int out_size, void* d_ws, size_t ws_size,
                              hipStream_t stream) {
    const float* x  = (const float*)d_in[0];
    const int* amask = (const int*)d_in[1];
    const float* Wq = (const float*)d_in[2];
    const float* Wk = (const float*)d_in[3];
    const float* Wv = (const float*)d_in[4];
    const float* Wo = (const float*)d_in[5];
    const float* bo = (const float*)d_in[6];
    float* out = (float*)d_out;

    const size_t XN = (size_t)B_ * S_ * H_;   // 8388608
    const size_t WN = (size_t)H_ * H_;        // 1048576

    char* ws = (char*)d_ws;
    unsigned short* xb  = (unsigned short*)ws;           ws += XN * 2;
    unsigned short* Wqb = (unsigned short*)ws;           ws += WN * 2;
    unsigned short* Wkb = (unsigned short*)ws;           ws += WN * 2;
    unsigned short* Wvb = (unsigned short*)ws;           ws += WN * 2;
    unsigned short* Wob = (unsigned short*)ws;           ws += WN * 2;
    unsigned short* Qb  = (unsigned short*)ws;           ws += XN * 2;
    unsigned short* Kb  = (unsigned short*)ws;           ws += XN * 2;
    unsigned short* Vb  = (unsigned short*)ws;           ws += XN * 2;
    unsigned short* Ab  = (unsigned short*)ws;           ws += XN * 2;

    cast_f32_bf16<<<(int)(XN / 4 / 256), 256, 0, stream>>>(x, xb, (int)(XN / 4));
    cast_f32_bf16<<<(int)(WN / 4 / 256), 256, 0, stream>>>(Wq, Wqb, (int)(WN / 4));
    cast_f32_bf16<<<(int)(WN / 4 / 256), 256, 0, stream>>>(Wk, Wkb, (int)(WN / 4));
    cast_f32_bf16<<<(int)(WN / 4 / 256), 256, 0, stream>>>(Wv, Wvb, (int)(WN / 4));
    cast_f32_bf16<<<(int)(WN / 4 / 256), 256, 0, stream>>>(Wo, Wob, (int)(WN / 4));

    gemm_qkv<<<dim3(64, 24), 256, 0, stream>>>(xb, Wqb, Wkb, Wvb, Qb, Kb, Vb);
    attn<<<dim3(B_ * NH_, S_ / 128), 256, 0, stream>>>(Qb, Kb, Vb, amask, Ab);
    gemm_out<<<dim3(64, 8), 256, 0, stream>>>(Ab, Wob, bo, out);
}

// Round 2
// 329.532 us; speedup vs baseline: 1.0431x; 1.0431x over previous
//
#include <hip/hip_runtime.h>

#define B_ 4
#define S_ 2048
#define H_ 1024
#define NH_ 16
#define HD_ 64
#define SCALE_ 0.125f

typedef __attribute__((ext_vector_type(8))) short bf16x8;
typedef __attribute__((ext_vector_type(4))) float f32x4;
typedef __attribute__((ext_vector_type(16))) float f32x16;

__device__ __forceinline__ unsigned short f2bf(float f) {
    unsigned u = __float_as_uint(f);
    unsigned r = (u + 0x7FFFu + ((u >> 16) & 1u)) >> 16;
    return (unsigned short)r;
}

// ---------------- cast fp32 -> bf16 (vectorized) ----------------
__global__ __launch_bounds__(256) void cast_f32_bf16(const float* __restrict__ in,
                                                     unsigned short* __restrict__ out, int n4) {
    int i = blockIdx.x * 256 + threadIdx.x;
    if (i < n4) {
        float4 v = reinterpret_cast<const float4*>(in)[i];
        ushort4 o;
        o.x = f2bf(v.x); o.y = f2bf(v.y); o.z = f2bf(v.z); o.w = f2bf(v.w);
        reinterpret_cast<ushort4*>(out)[i] = o;
    }
}

// ---------------- staging: 128 rows x 128 bytes, XOR slot-swizzled ----------------
// LDS(r, slot) holds global(r, slot ^ (r&7)); reader XORs the same way (involution).
__device__ __forceinline__ void stage128_swz(const char* g, int gstride, char* lds, int tid) {
    int wave = tid >> 6, lane = tid & 63;
#pragma unroll
    for (int j = 0; j < 4; ++j) {
        int o = ((wave * 4 + j) * 64 + lane) * 16;
        int r = o >> 7;
        int slot = (o >> 4) & 7;
        const char* src = g + (size_t)r * gstride + ((slot ^ (r & 7)) << 4);
        __builtin_amdgcn_global_load_lds((const __attribute__((address_space(1))) void*)src,
                                         (__attribute__((address_space(3))) void*)(lds + (wave * 4 + j) * 1024),
                                         16, 0, 0);
    }
}

__device__ __forceinline__ bf16x8 frag_swz(const char* lds, int row, int slot) {
    return *reinterpret_cast<const bf16x8*>(lds + row * 128 + (((slot) ^ (row & 7)) << 4));
}

// ---------------- fused QKV projection GEMM: C[M,N] = A[M,K] * W[N,K]^T ----------------
__global__ __launch_bounds__(256) void gemm_qkv(const unsigned short* __restrict__ xb,
                                                const unsigned short* __restrict__ Wq,
                                                const unsigned short* __restrict__ Wk,
                                                const unsigned short* __restrict__ Wv,
                                                unsigned short* __restrict__ Qo,
                                                unsigned short* __restrict__ Ko,
                                                unsigned short* __restrict__ Vo) {
    __shared__ __align__(16) char As[128 * 128];
    __shared__ __align__(16) char Bs[128 * 128];
    int tid = threadIdx.x, lane = tid & 63, wave = tid >> 6;
    int wr = wave >> 1, wc = wave & 1;
    int brow = blockIdx.x * 128;
    int mat = blockIdx.y >> 3;
    int bcol = (blockIdx.y & 7) * 128;
    const unsigned short* W = mat == 0 ? Wq : (mat == 1 ? Wk : Wv);
    unsigned short* O = mat == 0 ? Qo : (mat == 1 ? Ko : Vo);
    float oscale = (mat == 0) ? SCALE_ : 1.0f;  // fold attention scale into Q
    f32x4 acc[4][4] = {};
    const char* ga = (const char*)(xb + (size_t)brow * H_);
    const char* gb = (const char*)(W + (size_t)bcol * H_);
    int ro = lane & 15, kg = lane >> 4;
    for (int kt = 0; kt < H_ / 64; ++kt) {
        stage128_swz(ga + kt * 128, H_ * 2, As, tid);
        stage128_swz(gb + kt * 128, H_ * 2, Bs, tid);
        __syncthreads();
#pragma unroll
        for (int kk = 0; kk < 2; ++kk) {
            bf16x8 af[4], bfr[4];
#pragma unroll
            for (int m = 0; m < 4; ++m) af[m] = frag_swz(As, wr * 64 + m * 16 + ro, kk * 4 + kg);
#pragma unroll
            for (int n = 0; n < 4; ++n) bfr[n] = frag_swz(Bs, wc * 64 + n * 16 + ro, kk * 4 + kg);
#pragma unroll
            for (int m = 0; m < 4; ++m)
#pragma unroll
                for (int n = 0; n < 4; ++n)
                    acc[m][n] = __builtin_amdgcn_mfma_f32_16x16x32_bf16(af[m], bfr[n], acc[m][n], 0, 0, 0);
        }
        __syncthreads();
    }
#pragma unroll
    for (int m = 0; m < 4; ++m)
#pragma unroll
        for (int n = 0; n < 4; ++n)
#pragma unroll
            for (int i = 0; i < 4; ++i) {
                int row = brow + wr * 64 + m * 16 + kg * 4 + i;
                int col = bcol + wc * 64 + n * 16 + ro;
                O[(size_t)row * H_ + col] = f2bf(acc[m][n][i] * oscale);
            }
}

// ---------------- output projection GEMM + bias, fp32 out ----------------
__global__ __launch_bounds__(256) void gemm_out(const unsigned short* __restrict__ Ab,
                                                const unsigned short* __restrict__ Wo,
                                                const float* __restrict__ bo,
                                                float* __restrict__ out) {
    __shared__ __align__(16) char As[128 * 128];
    __shared__ __align__(16) char Bs[128 * 128];
    int tid = threadIdx.x, lane = tid & 63, wave = tid >> 6;
    int wr = wave >> 1, wc = wave & 1;
    int brow = blockIdx.x * 128;
    int bcol = blockIdx.y * 128;
    f32x4 acc[4][4] = {};
    const char* ga = (const char*)(Ab + (size_t)brow * H_);
    const char* gb = (const char*)(Wo + (size_t)bcol * H_);
    int ro = lane & 15, kg = lane >> 4;
    for (int kt = 0; kt < H_ / 64; ++kt) {
        stage128_swz(ga + kt * 128, H_ * 2, As, tid);
        stage128_swz(gb + kt * 128, H_ * 2, Bs, tid);
        __syncthreads();
#pragma unroll
        for (int kk = 0; kk < 2; ++kk) {
            bf16x8 af[4], bfr[4];
#pragma unroll
            for (int m = 0; m < 4; ++m) af[m] = frag_swz(As, wr * 64 + m * 16 + ro, kk * 4 + kg);
#pragma unroll
            for (int n = 0; n < 4; ++n) bfr[n] = frag_swz(Bs, wc * 64 + n * 16 + ro, kk * 4 + kg);
#pragma unroll
            for (int m = 0; m < 4; ++m)
#pragma unroll
                for (int n = 0; n < 4; ++n)
                    acc[m][n] = __builtin_amdgcn_mfma_f32_16x16x32_bf16(af[m], bfr[n], acc[m][n], 0, 0, 0);
        }
        __syncthreads();
    }
#pragma unroll
    for (int n = 0; n < 4; ++n) {
        int col = bcol + wc * 64 + n * 16 + ro;
        float bn = bo[col];
#pragma unroll
        for (int m = 0; m < 4; ++m)
#pragma unroll
            for (int i = 0; i < 4; ++i) {
                int row = brow + wr * 64 + m * 16 + kg * 4 + i;
                out[(size_t)row * H_ + col] = acc[m][n][i] + bn;
            }
    }
}

// ---------------- flash attention: swapped QK^T, in-register softmax ----------------
// grid: 1024 blocks (heavy-qb first). 4 waves x 32 q-rows, 32x32x16 MFMA.
// S^T = mfma(K,Q): lane owns one q-row (col=l31), kv per reg: (r&3)+8*(r>>2)+4*hi+32*n.
// P packs to bf16 in-register (cvt_pk + permlane32_swap) feeding PV's B-fragment.
// O accumulated transposed (O^T[d][q]); final transpose via LDS.
__global__ __launch_bounds__(256, 3) void attn(const unsigned short* __restrict__ Q,
                                               const unsigned short* __restrict__ K,
                                               const unsigned short* __restrict__ V,
                                               const int* __restrict__ amask,
                                               unsigned short* __restrict__ Ab) {
    __shared__ __align__(16) char Ksm[2 * 128 * 128];      // K double-buffer; O-transpose at end
    __shared__ __align__(16) unsigned short Vt[64 * 128];  // [d][kv] XOR-swizzled
    __shared__ unsigned char maskc[2048];

    int tid = threadIdx.x, lane = tid & 63, w = tid >> 6;
    int l31 = lane & 31, hi = lane >> 5, hi4 = hi * 4;
    int id = blockIdx.x;
    int qb = 15 - (id >> 6);          // heavy blocks dispatched first
    int bh = id & 63, b = bh >> 4, h = bh & 15;
    int brow = qb * 128;
    int w32l = w * 32 + l31;

    // hoist padding mask for this batch row into LDS (once)
    {
        const int4* am4 = reinterpret_cast<const int4*>(amask + b * S_);
        for (int i = tid; i < S_ / 4; i += 256) {
            int4 v = am4[i];
            uchar4 o;
            o.x = (v.x == 0); o.y = (v.y == 0); o.z = (v.z == 0); o.w = (v.w == 0);
            reinterpret_cast<uchar4*>(maskc)[i] = o;
        }
    }

    const unsigned short* Qg = Q + (size_t)(b * S_ + brow + w * 32 + l31) * H_ + h * HD_;
    const unsigned short* Kg = K + (size_t)b * S_ * H_ + h * HD_;
    const unsigned short* Vg = V + (size_t)b * S_ * H_ + h * HD_;

    // Q fragments (B-operand): lane l31 = q-col, k = kk*16 + hi*8 + j
    bf16x8 qf[4];
#pragma unroll
    for (int kk = 0; kk < 4; ++kk)
        qf[kk] = *reinterpret_cast<const bf16x8*>(Qg + kk * 16 + hi * 8);

    // prologue: stage K tile 0, prefetch V tile 0 into registers
    stage128_swz((const char*)Kg, H_ * 2, Ksm, tid);
    bf16x8 vreg[4];
#pragma unroll
    for (int c = 0; c < 4; ++c) {
        int cid = c * 256 + tid;
        int r = cid & 127, d0 = (cid >> 7) * 8;
        vreg[c] = *reinterpret_cast<const bf16x8*>(Vg + (size_t)r * H_ + d0);
    }

    f32x16 oacc[2];
#pragma unroll
    for (int nd = 0; nd < 2; ++nd)
#pragma unroll
        for (int j = 0; j < 16; ++j) oacc[nd][j] = 0.f;
    float mrun = -__builtin_inff(), lrun = 0.f;

    for (int t = 0; t <= qb; ++t) {
        int kv0 = t * 128;
        const char* Kc = Ksm + (t & 1) * 16384;

        // V registers -> Vt (conflict-free: lanes span contiguous r)
#pragma unroll
        for (int c = 0; c < 4; ++c) {
            int cid = c * 256 + tid;
            int r = cid & 127, d0 = (cid >> 7) * 8;
#pragma unroll
            for (int j = 0; j < 8; ++j) {
                int d = d0 + j;
                Vt[d * 128 + ((((r >> 3) ^ (d & 7)) << 3) | (r & 7))] = (unsigned short)vreg[c][j];
            }
        }
        __syncthreads();  // #1: K(t) staged (drained at prev barrier), Vt visible

        // prefetch K(t+1) into other buffer; latency hides under this tile's compute
        if (t < qb)
            stage128_swz((const char*)(Kg + (size_t)(kv0 + 128) * H_), H_ * 2,
                         Ksm + ((t + 1) & 1) * 16384, tid);
        // prefetch V(t+1) into registers
        {
            int kvn = (t < qb) ? kv0 + 128 : kv0;
#pragma unroll
            for (int c = 0; c < 4; ++c) {
                int cid = c * 256 + tid;
                int r = cid & 127, d0 = (cid >> 7) * 8;
                vreg[c] = *reinterpret_cast<const bf16x8*>(Vg + (size_t)(kvn + r) * H_ + d0);
            }
        }

        bool diag = (t == qb);
        int nmax = diag ? w : 3;       // causal: skip kv-tiles fully above the diagonal
        f32x16 sa[4];
#pragma unroll
        for (int n = 0; n < 4; ++n) {
            float init = (n <= nmax) ? 0.f : -1e30f;
#pragma unroll
            for (int j = 0; j < 16; ++j) sa[n][j] = init;
        }

        __builtin_amdgcn_s_setprio(1);
#pragma unroll
        for (int kk = 0; kk < 4; ++kk) {
#pragma unroll
            for (int n = 0; n < 4; ++n)
                if (n <= nmax) {
                    bf16x8 kf = frag_swz(Kc, 32 * n + l31, 2 * kk + hi);
                    sa[n] = __builtin_amdgcn_mfma_f32_32x32x16_bf16(kf, qf[kk], sa[n], 0, 0, 0);
                }
        }
        __builtin_amdgcn_s_setprio(0);

        // mask + lane-local row max
        float mx = -1e30f;
#pragma unroll
        for (int n = 0; n < 4; ++n) {
            if (n > nmax) continue;
#pragma unroll
            for (int u = 0; u < 4; ++u) {
                uchar4 mk = *reinterpret_cast<const uchar4*>(maskc + kv0 + 32 * n + 8 * u + hi4);
#pragma unroll
                for (int k = 0; k < 4; ++k) {
                    int r = 4 * u + k;
                    float s = sa[n][r];
                    unsigned char mbv = (k == 0) ? mk.x : (k == 1) ? mk.y : (k == 2) ? mk.z : mk.w;
                    int kvl = 32 * n + 8 * u + hi4 + k;
                    if (mbv) s = -1e9f;
                    if (diag && kvl > w32l) s = -1e9f;
                    sa[n][r] = s;
                    mx = fmaxf(mx, s);
                }
            }
        }
        mx = fmaxf(mx, __shfl_xor(mx, 32));
        float mnew = fmaxf(mrun, mx);
        float fsc = __expf(mrun - mnew);
        mrun = mnew;

        // exp + pack to bf16 words: wrd[n][u][t] = kv pair (32n+8u+4hi+2t, +1)
        float rs = 0.f;
        unsigned int wrd[4][4][2];
#pragma unroll
        for (int n = 0; n < 4; ++n) {
#pragma unroll
            for (int u = 0; u < 4; ++u) {
                float p0 = 0.f, p1 = 0.f, p2 = 0.f, p3 = 0.f;
                if (n <= nmax) {
                    p0 = __expf(sa[n][4 * u + 0] - mnew);
                    p1 = __expf(sa[n][4 * u + 1] - mnew);
                    p2 = __expf(sa[n][4 * u + 2] - mnew);
                    p3 = __expf(sa[n][4 * u + 3] - mnew);
                    rs += (p0 + p1) + (p2 + p3);
                }
                unsigned int w0, w1;
                asm("v_cvt_pk_bf16_f32 %0, %1, %2" : "=v"(w0) : "v"(p0), "v"(p1));
                asm("v_cvt_pk_bf16_f32 %0, %1, %2" : "=v"(w1) : "v"(p2), "v"(p3));
                wrd[n][u][0] = w0;
                wrd[n][u][1] = w1;
            }
        }
        rs += __shfl_xor(rs, 32);
        lrun = lrun * fsc + rs;
#pragma unroll
        for (int nd = 0; nd < 2; ++nd)
#pragma unroll
            for (int j = 0; j < 16; ++j) oacc[nd][j] *= fsc;

        // PV: O^T[d][q] += V^T x P^T. B-frag assembled via permlane32_swap.
        int kcmax = diag ? 2 * w + 1 : 7;
        __builtin_amdgcn_s_setprio(1);
#pragma unroll
        for (int kc = 0; kc < 8; ++kc) {
            if (kc > kcmax) continue;
            int n = kc >> 1, u0 = 2 * (kc & 1);
            unsigned int X0 = wrd[n][u0][0], Y0 = wrd[n][u0 + 1][0];
            unsigned int X1 = wrd[n][u0][1], Y1 = wrd[n][u0 + 1][1];
            asm("v_permlane32_swap_b32 %0, %1" : "+v"(X0), "+v"(Y0));
            asm("v_permlane32_swap_b32 %0, %1" : "+v"(X1), "+v"(Y1));
            union { unsigned int u[4]; bf16x8 v; } bu;
            bu.u[0] = X0; bu.u[1] = X1; bu.u[2] = Y0; bu.u[3] = Y1;
#pragma unroll
            for (int nd = 0; nd < 2; ++nd) {
                bf16x8 af = *reinterpret_cast<const bf16x8*>(
                    &Vt[(32 * nd + l31) * 128 + (((2 * kc + hi) ^ (l31 & 7)) << 3)]);
                oacc[nd] = __builtin_amdgcn_mfma_f32_32x32x16_bf16(af, bu.v, oacc[nd], 0, 0, 0);
            }
        }
        __builtin_amdgcn_s_setprio(0);
        __syncthreads();  // #2: PV reads done; drains K(t+1)/V(t+1) prefetch
    }

    // epilogue: divide by row sum, transpose O^T -> O via LDS, coalesced store
    float inv = 1.f / lrun;
    unsigned short* Osm = reinterpret_cast<unsigned short*>(Ksm);
#pragma unroll
    for (int nd = 0; nd < 2; ++nd)
#pragma unroll
        for (int r = 0; r < 16; ++r) {
            int d = 32 * nd + (r & 3) + 8 * (r >> 2) + hi4;
            Osm[w * 2048 + l31 * 64 + ((((d >> 3) ^ (l31 & 7)) << 3) | (d & 7))] =
                f2bf(oacc[nd][r] * inv);
        }
    __syncthreads();
#pragma unroll
    for (int wv = 0; wv < 4; ++wv) {
        int q = tid >> 3, j = tid & 7;
        bf16x8 vv = *reinterpret_cast<const bf16x8*>(Osm + wv * 2048 + q * 64 + ((j ^ (q & 7)) << 3));
        size_t row = (size_t)(b * S_ + brow + wv * 32 + q);
        *reinterpret_cast<bf16x8*>(Ab + row * H_ + h * HD_ + j * 8) = vv;
    }
}

extern "C" void kernel_launch(void* const* d_in, const int* in_sizes, int n_in,
                              void* d_out, int out_size, void* d_ws, size_t ws_size,
                              hipStream_t stream) {
    const float* x  = (const float*)d_in[0];
    const int* amask = (const int*)d_in[1];
    const float* Wq = (const float*)d_in[2];
    const float* Wk = (const float*)d_in[3];
    const float* Wv = (const float*)d_in[4];
    const float* Wo = (const float*)d_in[5];
    const float* bo = (const float*)d_in[6];
    float* out = (float*)d_out;

    const size_t XN = (size_t)B_ * S_ * H_;   // 8388608
    const size_t WN = (size_t)H_ * H_;        // 1048576

    char* ws = (char*)d_ws;
    unsigned short* xb  = (unsigned short*)ws;           ws += XN * 2;
    unsigned short* Wqb = (unsigned short*)ws;           ws += WN * 2;
    unsigned short* Wkb = (unsigned short*)ws;           ws += WN * 2;
    unsigned short* Wvb = (unsigned short*)ws;           ws += WN * 2;
    unsigned short* Wob = (unsigned short*)ws;           ws += WN * 2;
    unsigned short* Qb  = (unsigned short*)ws;           ws += XN * 2;
    unsigned short* Kb  = (unsigned short*)ws;           ws += XN * 2;
    unsigned short* Vb  = (unsigned short*)ws;           ws += XN * 2;
    unsigned short* Ab  = (unsigned short*)ws;           ws += XN * 2;

    cast_f32_bf16<<<(int)(XN / 4 / 256), 256, 0, stream>>>(x, xb, (int)(XN / 4));
    cast_f32_bf16<<<(int)(WN / 4 / 256), 256, 0, stream>>>(Wq, Wqb, (int)(WN / 4));
    cast_f32_bf16<<<(int)(WN / 4 / 256), 256, 0, stream>>>(Wk, Wkb, (int)(WN / 4));
    cast_f32_bf16<<<(int)(WN / 4 / 256), 256, 0, stream>>>(Wv, Wvb, (int)(WN / 4));
    cast_f32_bf16<<<(int)(WN / 4 / 256), 256, 0, stream>>>(Wo, Wob, (int)(WN / 4));

    gemm_qkv<<<dim3(64, 24), 256, 0, stream>>>(xb, Wqb, Wkb, Wvb, Qb, Kb, Vb);
    attn<<<1024, 256, 0, stream>>>(Qb, Kb, Vb, amask, Ab);
    gemm_out<<<dim3(64, 8), 256, 0, stream>>>(Ab, Wob, bo, out);
}

// Round 3
// 233.656 us; speedup vs baseline: 1.4712x; 1.4103x over previous
//
#include <hip/hip_runtime.h>

#define B_ 4
#define S_ 2048
#define H_ 1024
#define NH_ 16
#define HD_ 64
#define SCALE_ 0.125f

typedef __attribute__((ext_vector_type(8))) short bf16x8;
typedef __attribute__((ext_vector_type(4))) float f32x4;
typedef __attribute__((ext_vector_type(16))) float f32x16;

__device__ __forceinline__ unsigned short f2bf(float f) {
    unsigned u = __float_as_uint(f);
    unsigned r = (u + 0x7FFFu + ((u >> 16) & 1u)) >> 16;
    return (unsigned short)r;
}

// ---------------- cast fp32 -> bf16 (vectorized) ----------------
__global__ __launch_bounds__(256) void cast_f32_bf16(const float* __restrict__ in,
                                                     unsigned short* __restrict__ out, int n4) {
    int i = blockIdx.x * 256 + threadIdx.x;
    if (i < n4) {
        float4 v = reinterpret_cast<const float4*>(in)[i];
        ushort4 o;
        o.x = f2bf(v.x); o.y = f2bf(v.y); o.z = f2bf(v.z); o.w = f2bf(v.w);
        reinterpret_cast<ushort4*>(out)[i] = o;
    }
}

// ---------------- staging: 128 rows x 128 bytes, XOR slot-swizzled ----------------
// LDS(r, slot) holds global(r, slot ^ (r&7)); reader XORs the same way (involution).
__device__ __forceinline__ void stage128_swz(const char* g, int gstride, char* lds, int tid) {
    int wave = tid >> 6, lane = tid & 63;
#pragma unroll
    for (int j = 0; j < 4; ++j) {
        int o = ((wave * 4 + j) * 64 + lane) * 16;
        int r = o >> 7;
        int slot = (o >> 4) & 7;
        const char* src = g + (size_t)r * gstride + ((slot ^ (r & 7)) << 4);
        __builtin_amdgcn_global_load_lds((const __attribute__((address_space(1))) void*)src,
                                         (__attribute__((address_space(3))) void*)(lds + (wave * 4 + j) * 1024),
                                         16, 0, 0);
    }
}

__device__ __forceinline__ bf16x8 frag_swz(const char* lds, int row, int slot) {
    return *reinterpret_cast<const bf16x8*>(lds + row * 128 + (((slot) ^ (row & 7)) << 4));
}

// ---------------- fused QKV projection GEMM: C[M,N] = A[M,K] * W[N,K]^T ----------------
__global__ __launch_bounds__(256) void gemm_qkv(const unsigned short* __restrict__ xb,
                                                const unsigned short* __restrict__ Wq,
                                                const unsigned short* __restrict__ Wk,
                                                const unsigned short* __restrict__ Wv,
                                                unsigned short* __restrict__ Qo,
                                                unsigned short* __restrict__ Ko,
                                                unsigned short* __restrict__ Vo) {
    __shared__ __align__(16) char As[128 * 128];
    __shared__ __align__(16) char Bs[128 * 128];
    int tid = threadIdx.x, lane = tid & 63, wave = tid >> 6;
    int wr = wave >> 1, wc = wave & 1;
    int brow = blockIdx.x * 128;
    int mat = blockIdx.y >> 3;
    int bcol = (blockIdx.y & 7) * 128;
    const unsigned short* W = mat == 0 ? Wq : (mat == 1 ? Wk : Wv);
    unsigned short* O = mat == 0 ? Qo : (mat == 1 ? Ko : Vo);
    float oscale = (mat == 0) ? SCALE_ : 1.0f;  // fold attention scale into Q
    f32x4 acc[4][4] = {};
    const char* ga = (const char*)(xb + (size_t)brow * H_);
    const char* gb = (const char*)(W + (size_t)bcol * H_);
    int ro = lane & 15, kg = lane >> 4;
    for (int kt = 0; kt < H_ / 64; ++kt) {
        stage128_swz(ga + kt * 128, H_ * 2, As, tid);
        stage128_swz(gb + kt * 128, H_ * 2, Bs, tid);
        __syncthreads();
#pragma unroll
        for (int kk = 0; kk < 2; ++kk) {
            bf16x8 af[4], bfr[4];
#pragma unroll
            for (int m = 0; m < 4; ++m) af[m] = frag_swz(As, wr * 64 + m * 16 + ro, kk * 4 + kg);
#pragma unroll
            for (int n = 0; n < 4; ++n) bfr[n] = frag_swz(Bs, wc * 64 + n * 16 + ro, kk * 4 + kg);
#pragma unroll
            for (int m = 0; m < 4; ++m)
#pragma unroll
                for (int n = 0; n < 4; ++n)
                    acc[m][n] = __builtin_amdgcn_mfma_f32_16x16x32_bf16(af[m], bfr[n], acc[m][n], 0, 0, 0);
        }
        __syncthreads();
    }
#pragma unroll
    for (int m = 0; m < 4; ++m)
#pragma unroll
        for (int n = 0; n < 4; ++n)
#pragma unroll
            for (int i = 0; i < 4; ++i) {
                int row = brow + wr * 64 + m * 16 + kg * 4 + i;
                int col = bcol + wc * 64 + n * 16 + ro;
                O[(size_t)row * H_ + col] = f2bf(acc[m][n][i] * oscale);
            }
}

// ---------------- output projection GEMM + bias, fp32 out ----------------
__global__ __launch_bounds__(256) void gemm_out(const unsigned short* __restrict__ Ab,
                                                const unsigned short* __restrict__ Wo,
                                                const float* __restrict__ bo,
                                                float* __restrict__ out) {
    __shared__ __align__(16) char As[128 * 128];
    __shared__ __align__(16) char Bs[128 * 128];
    int tid = threadIdx.x, lane = tid & 63, wave = tid >> 6;
    int wr = wave >> 1, wc = wave & 1;
    int brow = blockIdx.x * 128;
    int bcol = blockIdx.y * 128;
    f32x4 acc[4][4] = {};
    const char* ga = (const char*)(Ab + (size_t)brow * H_);
    const char* gb = (const char*)(Wo + (size_t)bcol * H_);
    int ro = lane & 15, kg = lane >> 4;
    for (int kt = 0; kt < H_ / 64; ++kt) {
        stage128_swz(ga + kt * 128, H_ * 2, As, tid);
        stage128_swz(gb + kt * 128, H_ * 2, Bs, tid);
        __syncthreads();
#pragma unroll
        for (int kk = 0; kk < 2; ++kk) {
            bf16x8 af[4], bfr[4];
#pragma unroll
            for (int m = 0; m < 4; ++m) af[m] = frag_swz(As, wr * 64 + m * 16 + ro, kk * 4 + kg);
#pragma unroll
            for (int n = 0; n < 4; ++n) bfr[n] = frag_swz(Bs, wc * 64 + n * 16 + ro, kk * 4 + kg);
#pragma unroll
            for (int m = 0; m < 4; ++m)
#pragma unroll
                for (int n = 0; n < 4; ++n)
                    acc[m][n] = __builtin_amdgcn_mfma_f32_16x16x32_bf16(af[m], bfr[n], acc[m][n], 0, 0, 0);
        }
        __syncthreads();
    }
#pragma unroll
    for (int n = 0; n < 4; ++n) {
        int col = bcol + wc * 64 + n * 16 + ro;
        float bn = bo[col];
#pragma unroll
        for (int m = 0; m < 4; ++m)
#pragma unroll
            for (int i = 0; i < 4; ++i) {
                int row = brow + wr * 64 + m * 16 + kg * 4 + i;
                out[(size_t)row * H_ + col] = acc[m][n][i] + bn;
            }
    }
}

// ---------------- flash attention: swapped QK^T, in-register softmax ----------------
// grid: 1024 blocks (heavy-qb first). 4 waves x 32 q-rows, 32x32x16 MFMA.
// S^T = mfma(K,Q): lane owns one q-row (col=l31), kv per reg: (r&3)+8*(r>>2)+4*hi+32*n.
// P packs to bf16 in-register (cvt_pk + permlane32_swap) feeding PV's B-fragment.
// Per-n fusion keeps only 8 packed words live; PV(n) MFMA overlaps exp(n+1) VALU.
// O accumulated transposed (O^T[d][q]); final transpose via LDS.
__global__ __launch_bounds__(256) void attn(const unsigned short* __restrict__ Q,
                                            const unsigned short* __restrict__ K,
                                            const unsigned short* __restrict__ V,
                                            const int* __restrict__ amask,
                                            unsigned short* __restrict__ Ab) {
    __shared__ __align__(16) char Ksm[2 * 128 * 128];      // K double-buffer; O-transpose at end
    __shared__ __align__(16) unsigned short Vt[64 * 128];  // [d][kv] XOR-swizzled
    __shared__ unsigned char maskc[2048];

    int tid = threadIdx.x, lane = tid & 63, w = tid >> 6;
    int l31 = lane & 31, hi = lane >> 5, hi4 = hi * 4;
    int id = blockIdx.x;
    int qb = 15 - (id >> 6);          // heavy blocks dispatched first
    int bh = id & 63, b = bh >> 4, h = bh & 15;
    int brow = qb * 128;
    int w32l = w * 32 + l31;

    // hoist padding mask for this batch row into LDS (once)
    {
        const int4* am4 = reinterpret_cast<const int4*>(amask + b * S_);
        for (int i = tid; i < S_ / 4; i += 256) {
            int4 v = am4[i];
            uchar4 o;
            o.x = (v.x == 0); o.y = (v.y == 0); o.z = (v.z == 0); o.w = (v.w == 0);
            reinterpret_cast<uchar4*>(maskc)[i] = o;
        }
    }

    const unsigned short* Qg = Q + (size_t)(b * S_ + brow + w * 32 + l31) * H_ + h * HD_;
    const unsigned short* Kg = K + (size_t)b * S_ * H_ + h * HD_;
    const unsigned short* Vg = V + (size_t)b * S_ * H_ + h * HD_;

    // Q fragments (B-operand): lane l31 = q-col, k = kk*16 + hi*8 + j
    bf16x8 qf[4];
#pragma unroll
    for (int kk = 0; kk < 4; ++kk)
        qf[kk] = *reinterpret_cast<const bf16x8*>(Qg + kk * 16 + hi * 8);

    // prologue: stage K tile 0, prefetch V tile 0 into registers
    stage128_swz((const char*)Kg, H_ * 2, Ksm, tid);
    bf16x8 vreg[4];
#pragma unroll
    for (int c = 0; c < 4; ++c) {
        int cid = c * 256 + tid;
        int r = cid & 127, d0 = (cid >> 7) * 8;
        vreg[c] = *reinterpret_cast<const bf16x8*>(Vg + (size_t)r * H_ + d0);
    }

    f32x16 oacc[2];
#pragma unroll
    for (int nd = 0; nd < 2; ++nd)
#pragma unroll
        for (int j = 0; j < 16; ++j) oacc[nd][j] = 0.f;
    float mrun = -__builtin_inff(), lrun = 0.f;

    for (int t = 0; t <= qb; ++t) {
        int kv0 = t * 128;
        const char* Kc = Ksm + (t & 1) * 16384;

        // V registers -> Vt (conflict-free: lanes span contiguous r)
#pragma unroll
        for (int c = 0; c < 4; ++c) {
            int cid = c * 256 + tid;
            int r = cid & 127, d0 = (cid >> 7) * 8;
#pragma unroll
            for (int j = 0; j < 8; ++j) {
                int d = d0 + j;
                Vt[d * 128 + ((((r >> 3) ^ (d & 7)) << 3) | (r & 7))] = (unsigned short)vreg[c][j];
            }
        }
        __syncthreads();  // #1: K(t) staged (drained at prev barrier), Vt visible

        // prefetch K(t+1) into other buffer; latency hides under this tile's compute
        if (t < qb)
            stage128_swz((const char*)(Kg + (size_t)(kv0 + 128) * H_), H_ * 2,
                         Ksm + ((t + 1) & 1) * 16384, tid);
        // prefetch V(t+1) into registers
        {
            int kvn = (t < qb) ? kv0 + 128 : kv0;
#pragma unroll
            for (int c = 0; c < 4; ++c) {
                int cid = c * 256 + tid;
                int r = cid & 127, d0 = (cid >> 7) * 8;
                vreg[c] = *reinterpret_cast<const bf16x8*>(Vg + (size_t)(kvn + r) * H_ + d0);
            }
        }

        bool diag = (t == qb);
        int nmax = diag ? w : 3;       // causal: skip kv-tiles fully above the diagonal
        f32x16 sa[4];
#pragma unroll
        for (int n = 0; n < 4; ++n) {
            float init = (n <= nmax) ? 0.f : -1e30f;
#pragma unroll
            for (int j = 0; j < 16; ++j) sa[n][j] = init;
        }

        __builtin_amdgcn_s_setprio(1);
#pragma unroll
        for (int kk = 0; kk < 4; ++kk) {
#pragma unroll
            for (int n = 0; n < 4; ++n)
                if (n <= nmax) {
                    bf16x8 kf = frag_swz(Kc, 32 * n + l31, 2 * kk + hi);
                    sa[n] = __builtin_amdgcn_mfma_f32_32x32x16_bf16(kf, qf[kk], sa[n], 0, 0, 0);
                }
        }
        __builtin_amdgcn_s_setprio(0);

        // mask + lane-local row max
        float mx = -1e30f;
#pragma unroll
        for (int n = 0; n < 4; ++n) {
            if (n > nmax) continue;
#pragma unroll
            for (int u = 0; u < 4; ++u) {
                uchar4 mk = *reinterpret_cast<const uchar4*>(maskc + kv0 + 32 * n + 8 * u + hi4);
#pragma unroll
                for (int k = 0; k < 4; ++k) {
                    int r = 4 * u + k;
                    float s = sa[n][r];
                    unsigned char mbv = (k == 0) ? mk.x : (k == 1) ? mk.y : (k == 2) ? mk.z : mk.w;
                    int kvl = 32 * n + 8 * u + hi4 + k;
                    if (mbv) s = -1e9f;
                    if (diag && kvl > w32l) s = -1e9f;
                    sa[n][r] = s;
                    mx = fmaxf(mx, s);
                }
            }
        }
        mx = fmaxf(mx, __shfl_xor(mx, 32));
        float mnew = fmaxf(mrun, mx);
        float fsc = __expf(mrun - mnew);
        mrun = mnew;

        // rescale O once per tile
#pragma unroll
        for (int nd = 0; nd < 2; ++nd)
#pragma unroll
            for (int j = 0; j < 16; ++j) oacc[nd][j] *= fsc;

        // fused per-n: exp -> pack bf16 -> permlane -> PV MFMA (only 8 words live)
        float rs = 0.f;
        __builtin_amdgcn_s_setprio(1);
#pragma unroll
        for (int n = 0; n < 4; ++n) {
            if (n > nmax) continue;
            unsigned int wrd[4][2];
#pragma unroll
            for (int u = 0; u < 4; ++u) {
                float p0 = __expf(sa[n][4 * u + 0] - mnew);
                float p1 = __expf(sa[n][4 * u + 1] - mnew);
                float p2 = __expf(sa[n][4 * u + 2] - mnew);
                float p3 = __expf(sa[n][4 * u + 3] - mnew);
                rs += (p0 + p1) + (p2 + p3);
                asm("v_cvt_pk_bf16_f32 %0, %1, %2" : "=v"(wrd[u][0]) : "v"(p0), "v"(p1));
                asm("v_cvt_pk_bf16_f32 %0, %1, %2" : "=v"(wrd[u][1]) : "v"(p2), "v"(p3));
            }
#pragma unroll
            for (int half = 0; half < 2; ++half) {
                int u0 = 2 * half;
                unsigned int X0 = wrd[u0][0], Y0 = wrd[u0 + 1][0];
                unsigned int X1 = wrd[u0][1], Y1 = wrd[u0 + 1][1];
                asm("v_permlane32_swap_b32 %0, %1" : "+v"(X0), "+v"(Y0));
                asm("v_permlane32_swap_b32 %0, %1" : "+v"(X1), "+v"(Y1));
                union { unsigned int u[4]; bf16x8 v; } bu;
                bu.u[0] = X0; bu.u[1] = X1; bu.u[2] = Y0; bu.u[3] = Y1;
                int kc = 2 * n + half;
#pragma unroll
                for (int nd = 0; nd < 2; ++nd) {
                    bf16x8 af = *reinterpret_cast<const bf16x8*>(
                        &Vt[(32 * nd + l31) * 128 + (((2 * kc + hi) ^ (l31 & 7)) << 3)]);
                    oacc[nd] = __builtin_amdgcn_mfma_f32_32x32x16_bf16(af, bu.v, oacc[nd], 0, 0, 0);
                }
            }
        }
        __builtin_amdgcn_s_setprio(0);

        rs += __shfl_xor(rs, 32);
        lrun = lrun * fsc + rs;
        __syncthreads();  // #2: PV reads done; drains K(t+1)/V(t+1) prefetch
    }

    // epilogue: divide by row sum, transpose O^T -> O via LDS, coalesced store
    float inv = 1.f / lrun;
    unsigned short* Osm = reinterpret_cast<unsigned short*>(Ksm);
#pragma unroll
    for (int nd = 0; nd < 2; ++nd)
#pragma unroll
        for (int r = 0; r < 16; ++r) {
            int d = 32 * nd + (r & 3) + 8 * (r >> 2) + hi4;
            Osm[w * 2048 + l31 * 64 + ((((d >> 3) ^ (l31 & 7)) << 3) | (d & 7))] =
                f2bf(oacc[nd][r] * inv);
        }
    __syncthreads();
#pragma unroll
    for (int wv = 0; wv < 4; ++wv) {
        int q = tid >> 3, j = tid & 7;
        bf16x8 vv = *reinterpret_cast<const bf16x8*>(Osm + wv * 2048 + q * 64 + ((j ^ (q & 7)) << 3));
        size_t row = (size_t)(b * S_ + brow + wv * 32 + q);
        *reinterpret_cast<bf16x8*>(Ab + row * H_ + h * HD_ + j * 8) = vv;
    }
}

extern "C" void kernel_launch(void* const* d_in, const int* in_sizes, int n_in,
                              void* d_out, int out_size, void* d_ws, size_t ws_size,
                              hipStream_t stream) {
    const float* x  = (const float*)d_in[0];
    const int* amask = (const int*)d_in[1];
    const float* Wq = (const float*)d_in[2];
    const float* Wk = (const float*)d_in[3];
    const float* Wv = (const float*)d_in[4];
    const float* Wo = (const float*)d_in[5];
    const float* bo = (const float*)d_in[6];
    float* out = (float*)d_out;

    const size_t XN = (size_t)B_ * S_ * H_;   // 8388608
    const size_t WN = (size_t)H_ * H_;        // 1048576

    char* ws = (char*)d_ws;
    unsigned short* xb  = (unsigned short*)ws;           ws += XN * 2;
    unsigned short* Wqb = (unsigned short*)ws;           ws += WN * 2;
    unsigned short* Wkb = (unsigned short*)ws;           ws += WN * 2;
    unsigned short* Wvb = (unsigned short*)ws;           ws += WN * 2;
    unsigned short* Wob = (unsigned short*)ws;           ws += WN * 2;
    unsigned short* Qb  = (unsigned short*)ws;           ws += XN * 2;
    unsigned short* Kb  = (unsigned short*)ws;           ws += XN * 2;
    unsigned short* Vb  = (unsigned short*)ws;           ws += XN * 2;
    unsigned short* Ab  = (unsigned short*)ws;           ws += XN * 2;

    cast_f32_bf16<<<(int)(XN / 4 / 256), 256, 0, stream>>>(x, xb, (int)(XN / 4));
    cast_f32_bf16<<<(int)(WN / 4 / 256), 256, 0, stream>>>(Wq, Wqb, (int)(WN / 4));
    cast_f32_bf16<<<(int)(WN / 4 / 256), 256, 0, stream>>>(Wk, Wkb, (int)(WN / 4));
    cast_f32_bf16<<<(int)(WN / 4 / 256), 256, 0, stream>>>(Wv, Wvb, (int)(WN / 4));
    cast_f32_bf16<<<(int)(WN / 4 / 256), 256, 0, stream>>>(Wo, Wob, (int)(WN / 4));

    gemm_qkv<<<dim3(64, 24), 256, 0, stream>>>(xb, Wqb, Wkb, Wvb, Qb, Kb, Vb);
    attn<<<1024, 256, 0, stream>>>(Qb, Kb, Vb, amask, Ab);
    gemm_out<<<dim3(64, 8), 256, 0, stream>>>(Ab, Wob, bo, out);
}

// Round 4
// 201.709 us; speedup vs baseline: 1.7042x; 1.1584x over previous
//
#include <hip/hip_runtime.h>

#define B_ 4
#define S_ 2048
#define H_ 1024
#define NH_ 16
#define HD_ 64
// SCALE * log2(e): QK^T lands in log2 domain; exp -> v_exp_f32 (2^x) directly
#define QSCALE_ 0.1803368801111204f

typedef __attribute__((ext_vector_type(8))) short bf16x8;
typedef __attribute__((ext_vector_type(4))) float f32x4;
typedef __attribute__((ext_vector_type(16))) float f32x16;

__device__ __forceinline__ unsigned short f2bf(float f) {
    unsigned u = __float_as_uint(f);
    unsigned r = (u + 0x7FFFu + ((u >> 16) & 1u)) >> 16;
    return (unsigned short)r;
}
__device__ __forceinline__ float exp2f_hw(float x) { return __builtin_amdgcn_exp2f(x); }

// ---------------- cast fp32 -> bf16 (vectorized) ----------------
__global__ __launch_bounds__(256) void cast_f32_bf16(const float* __restrict__ in,
                                                     unsigned short* __restrict__ out, int n4) {
    int i = blockIdx.x * 256 + threadIdx.x;
    if (i < n4) {
        float4 v = reinterpret_cast<const float4*>(in)[i];
        ushort4 o;
        o.x = f2bf(v.x); o.y = f2bf(v.y); o.z = f2bf(v.z); o.w = f2bf(v.w);
        reinterpret_cast<ushort4*>(out)[i] = o;
    }
}

// ---------------- staging: rows x 128 bytes, XOR slot-swizzled ----------------
__device__ __forceinline__ void stage128_swz(const char* g, int gstride, char* lds, int tid) {
    int wave = tid >> 6, lane = tid & 63;
#pragma unroll
    for (int j = 0; j < 4; ++j) {
        int o = ((wave * 4 + j) * 64 + lane) * 16;
        int r = o >> 7;
        int slot = (o >> 4) & 7;
        const char* src = g + (size_t)r * gstride + ((slot ^ (r & 7)) << 4);
        __builtin_amdgcn_global_load_lds((const __attribute__((address_space(1))) void*)src,
                                         (__attribute__((address_space(3))) void*)(lds + (wave * 4 + j) * 1024),
                                         16, 0, 0);
    }
}
__device__ __forceinline__ void stage64_swz(const char* g, int gstride, char* lds, int tid) {
    int wave = tid >> 6, lane = tid & 63;
#pragma unroll
    for (int j = 0; j < 2; ++j) {
        int o = ((wave * 2 + j) * 64 + lane) * 16;
        int r = o >> 7;
        int slot = (o >> 4) & 7;
        const char* src = g + (size_t)r * gstride + ((slot ^ (r & 7)) << 4);
        __builtin_amdgcn_global_load_lds((const __attribute__((address_space(1))) void*)src,
                                         (__attribute__((address_space(3))) void*)(lds + (wave * 2 + j) * 1024),
                                         16, 0, 0);
    }
}

__device__ __forceinline__ bf16x8 frag_swz(const char* lds, int row, int slot) {
    return *reinterpret_cast<const bf16x8*>(lds + row * 128 + (((slot) ^ (row & 7)) << 4));
}

// ---------------- fused QKV projection GEMM: C[M,N] = A[M,K] * W[N,K]^T ----------------
__global__ __launch_bounds__(256) void gemm_qkv(const unsigned short* __restrict__ xb,
                                                const unsigned short* __restrict__ Wq,
                                                const unsigned short* __restrict__ Wk,
                                                const unsigned short* __restrict__ Wv,
                                                unsigned short* __restrict__ Qo,
                                                unsigned short* __restrict__ Ko,
                                                unsigned short* __restrict__ Vo) {
    __shared__ __align__(16) char As[128 * 128];
    __shared__ __align__(16) char Bs[128 * 128];
    int tid = threadIdx.x, lane = tid & 63, wave = tid >> 6;
    int wr = wave >> 1, wc = wave & 1;
    int brow = blockIdx.x * 128;
    int mat = blockIdx.y >> 3;
    int bcol = (blockIdx.y & 7) * 128;
    const unsigned short* W = mat == 0 ? Wq : (mat == 1 ? Wk : Wv);
    unsigned short* O = mat == 0 ? Qo : (mat == 1 ? Ko : Vo);
    float oscale = (mat == 0) ? QSCALE_ : 1.0f;  // fold attn scale + log2e into Q
    f32x4 acc[4][4] = {};
    const char* ga = (const char*)(xb + (size_t)brow * H_);
    const char* gb = (const char*)(W + (size_t)bcol * H_);
    int ro = lane & 15, kg = lane >> 4;
    for (int kt = 0; kt < H_ / 64; ++kt) {
        stage128_swz(ga + kt * 128, H_ * 2, As, tid);
        stage128_swz(gb + kt * 128, H_ * 2, Bs, tid);
        __syncthreads();
#pragma unroll
        for (int kk = 0; kk < 2; ++kk) {
            bf16x8 af[4], bfr[4];
#pragma unroll
            for (int m = 0; m < 4; ++m) af[m] = frag_swz(As, wr * 64 + m * 16 + ro, kk * 4 + kg);
#pragma unroll
            for (int n = 0; n < 4; ++n) bfr[n] = frag_swz(Bs, wc * 64 + n * 16 + ro, kk * 4 + kg);
#pragma unroll
            for (int m = 0; m < 4; ++m)
#pragma unroll
                for (int n = 0; n < 4; ++n)
                    acc[m][n] = __builtin_amdgcn_mfma_f32_16x16x32_bf16(af[m], bfr[n], acc[m][n], 0, 0, 0);
        }
        __syncthreads();
    }
#pragma unroll
    for (int m = 0; m < 4; ++m)
#pragma unroll
        for (int n = 0; n < 4; ++n)
#pragma unroll
            for (int i = 0; i < 4; ++i) {
                int row = brow + wr * 64 + m * 16 + kg * 4 + i;
                int col = bcol + wc * 64 + n * 16 + ro;
                O[(size_t)row * H_ + col] = f2bf(acc[m][n][i] * oscale);
            }
}

// ---------------- output projection GEMM + bias, fp32 out ----------------
__global__ __launch_bounds__(256) void gemm_out(const unsigned short* __restrict__ Ab,
                                                const unsigned short* __restrict__ Wo,
                                                const float* __restrict__ bo,
                                                float* __restrict__ out) {
    __shared__ __align__(16) char As[128 * 128];
    __shared__ __align__(16) char Bs[128 * 128];
    int tid = threadIdx.x, lane = tid & 63, wave = tid >> 6;
    int wr = wave >> 1, wc = wave & 1;
    int brow = blockIdx.x * 128;
    int bcol = blockIdx.y * 128;
    f32x4 acc[4][4] = {};
    const char* ga = (const char*)(Ab + (size_t)brow * H_);
    const char* gb = (const char*)(Wo + (size_t)bcol * H_);
    int ro = lane & 15, kg = lane >> 4;
    for (int kt = 0; kt < H_ / 64; ++kt) {
        stage128_swz(ga + kt * 128, H_ * 2, As, tid);
        stage128_swz(gb + kt * 128, H_ * 2, Bs, tid);
        __syncthreads();
#pragma unroll
        for (int kk = 0; kk < 2; ++kk) {
            bf16x8 af[4], bfr[4];
#pragma unroll
            for (int m = 0; m < 4; ++m) af[m] = frag_swz(As, wr * 64 + m * 16 + ro, kk * 4 + kg);
#pragma unroll
            for (int n = 0; n < 4; ++n) bfr[n] = frag_swz(Bs, wc * 64 + n * 16 + ro, kk * 4 + kg);
#pragma unroll
            for (int m = 0; m < 4; ++m)
#pragma unroll
                for (int n = 0; n < 4; ++n)
                    acc[m][n] = __builtin_amdgcn_mfma_f32_16x16x32_bf16(af[m], bfr[n], acc[m][n], 0, 0, 0);
        }
        __syncthreads();
    }
#pragma unroll
    for (int n = 0; n < 4; ++n) {
        int col = bcol + wc * 64 + n * 16 + ro;
        float bn = bo[col];
#pragma unroll
        for (int m = 0; m < 4; ++m)
#pragma unroll
            for (int i = 0; i < 4; ++i) {
                int row = brow + wr * 64 + m * 16 + kg * 4 + i;
                out[(size_t)row * H_ + col] = acc[m][n][i] + bn;
            }
    }
}

// ---------------- flash attention: swapped QK^T, in-register softmax, KVBLK=64 ----------------
// grid: 1024 blocks (heavy-qb first). 4 waves x 32 q-rows, 32x32x16 MFMA.
// S^T = mfma(K,Q): lane owns q-row (col=l31); kv reg map: (r&3)+8*(r>>2)+4*hi+32*n.
// Causal resolved per 32x32 sub-block: full / diagonal (once per wave) / skip.
// Padding mask gated by per-tile anyz byte (hot loop clean when mask all-ones).
// Strict defer-rescale: skip O-rescale when tile max doesn't grow (exact).
__global__ __launch_bounds__(256) void attn(const unsigned short* __restrict__ Q,
                                            const unsigned short* __restrict__ K,
                                            const unsigned short* __restrict__ V,
                                            const int* __restrict__ amask,
                                            unsigned short* __restrict__ Ab) {
    __shared__ __align__(16) char Ksm[2 * 64 * 128];       // K double-buffer (16KB); O-transpose at end
    __shared__ __align__(16) unsigned short Vt[64 * 64];   // [d][kv] XOR-swizzled (8KB)
    __shared__ unsigned char maskc[2048];
    __shared__ unsigned char anyz[32];

    int tid = threadIdx.x, lane = tid & 63, w = tid >> 6;
    int l31 = lane & 31, hi = lane >> 5, hi4 = hi * 4;
    int id = blockIdx.x;
    int qb = 15 - (id >> 6);          // heavy blocks dispatched first
    int bh = id & 63, b = bh >> 4, h = bh & 15;
    int brow = qb * 128;
    int Qwg = brow + w * 32;          // wave's q-base; lane's q-row = Qwg + l31

    // per-lane causal bitmask for the diagonal 32x32 sub-block (kv_local > q_local)
    unsigned cm = 0;
#pragma unroll
    for (int r = 0; r < 16; ++r)
        if (((r & 3) + 8 * (r >> 2) + hi4) > l31) cm |= (1u << r);

    // hoist padding mask for this batch row into LDS (once)
    {
        const int4* am4 = reinterpret_cast<const int4*>(amask + b * S_);
        for (int i = tid; i < S_ / 4; i += 256) {
            int4 v = am4[i];
            uchar4 o;
            o.x = (v.x == 0); o.y = (v.y == 0); o.z = (v.z == 0); o.w = (v.w == 0);
            reinterpret_cast<uchar4*>(maskc)[i] = o;
        }
    }
    __syncthreads();
    if (tid < 32) {  // per-64-kv "any masked" byte
        const unsigned* mw = reinterpret_cast<const unsigned*>(maskc + tid * 64);
        unsigned o = 0;
#pragma unroll
        for (int i = 0; i < 16; ++i) o |= mw[i];
        anyz[tid] = o ? 1 : 0;
    }

    const unsigned short* Qg = Q + (size_t)(b * S_ + Qwg + l31) * H_ + h * HD_;
    const unsigned short* Kg = K + (size_t)b * S_ * H_ + h * HD_;
    const unsigned short* Vg = V + (size_t)b * S_ * H_ + h * HD_;

    // Q fragments (B-operand): lane l31 = q-col, k = kk*16 + hi*8 + j
    bf16x8 qf[4];
#pragma unroll
    for (int kk = 0; kk < 4; ++kk)
        qf[kk] = *reinterpret_cast<const bf16x8*>(Qg + kk * 16 + hi * 8);

    // prologue: stage K tile 0, prefetch V tile 0 into registers
    stage64_swz((const char*)Kg, H_ * 2, Ksm, tid);
    bf16x8 vreg[2];
#pragma unroll
    for (int c = 0; c < 2; ++c) {
        int cid = c * 256 + tid;
        int r = cid & 63, d0 = (cid >> 6) * 8;
        vreg[c] = *reinterpret_cast<const bf16x8*>(Vg + (size_t)r * H_ + d0);
    }

    f32x16 oacc[2];
#pragma unroll
    for (int nd = 0; nd < 2; ++nd)
#pragma unroll
        for (int j = 0; j < 16; ++j) oacc[nd][j] = 0.f;
    float mrun = -__builtin_inff(), lrun = 0.f;

    int T = 2 * qb + 2;
    for (int t = 0; t < T; ++t) {
        int kv0 = t * 64;
        const char* Kc = Ksm + (t & 1) * 8192;

        // V registers -> Vt (swizzled; 2-way-free banks on write)
#pragma unroll
        for (int c = 0; c < 2; ++c) {
            int cid = c * 256 + tid;
            int r = cid & 63, d0 = (cid >> 6) * 8;
#pragma unroll
            for (int j = 0; j < 8; ++j) {
                int d = d0 + j;
                Vt[d * 64 + ((((r >> 3) ^ (d & 7)) << 3) | (r & 7))] = (unsigned short)vreg[c][j];
            }
        }
        __syncthreads();  // #1: K(t) staged (drained at prev barrier), Vt + anyz visible

        // prefetch K(t+1) (drains at barrier #2); prefetch V(t+1) into registers
        if (t + 1 < T)
            stage64_swz((const char*)(Kg + (size_t)(kv0 + 64) * H_), H_ * 2,
                        Ksm + ((t + 1) & 1) * 8192, tid);
        {
            int kvn = (t + 1 < T) ? kv0 + 64 : kv0;
#pragma unroll
            for (int c = 0; c < 2; ++c) {
                int cid = c * 256 + tid;
                int r = cid & 63, d0 = (cid >> 6) * 8;
                vreg[c] = *reinterpret_cast<const bf16x8*>(Vg + (size_t)(kvn + r) * H_ + d0);
            }
        }

        int c0 = kv0, c1 = kv0 + 32;
        if (c0 <= Qwg) {             // wave-uniform: any visible work in this tile
            bool vis1 = (c1 <= Qwg);
            f32x16 sa[2];
#pragma unroll
            for (int n = 0; n < 2; ++n)
#pragma unroll
                for (int j = 0; j < 16; ++j) sa[n][j] = 0.f;

            __builtin_amdgcn_s_setprio(1);
#pragma unroll
            for (int kk = 0; kk < 4; ++kk) {
                bf16x8 kf0 = frag_swz(Kc, l31, 2 * kk + hi);
                sa[0] = __builtin_amdgcn_mfma_f32_32x32x16_bf16(kf0, qf[kk], sa[0], 0, 0, 0);
                if (vis1) {
                    bf16x8 kf1 = frag_swz(Kc, 32 + l31, 2 * kk + hi);
                    sa[1] = __builtin_amdgcn_mfma_f32_32x32x16_bf16(kf1, qf[kk], sa[1], 0, 0, 0);
                }
            }
            __builtin_amdgcn_s_setprio(0);

            // causal: diagonal sub-block occurs at most once per wave
            if (c0 == Qwg) {
#pragma unroll
                for (int r = 0; r < 16; ++r)
                    sa[0][r] = (cm & (1u << r)) ? -1e9f : sa[0][r];
            }
            if (vis1 && c1 == Qwg) {
#pragma unroll
                for (int r = 0; r < 16; ++r)
                    sa[1][r] = (cm & (1u << r)) ? -1e9f : sa[1][r];
            }
            // padding mask (skipped when this 64-kv group is all-ones)
            if (anyz[t]) {
#pragma unroll
                for (int n = 0; n < 2; ++n) {
                    if (n == 1 && !vis1) break;
#pragma unroll
                    for (int u = 0; u < 4; ++u) {
                        uchar4 mk = *reinterpret_cast<const uchar4*>(maskc + kv0 + 32 * n + 8 * u + hi4);
                        if (mk.x) sa[n][4 * u + 0] = -1e9f;
                        if (mk.y) sa[n][4 * u + 1] = -1e9f;
                        if (mk.z) sa[n][4 * u + 2] = -1e9f;
                        if (mk.w) sa[n][4 * u + 3] = -1e9f;
                    }
                }
            }

            // lane-local row max (+1 cross-half shuffle)
            float mx = -1e30f;
#pragma unroll
            for (int r = 0; r < 16; ++r) mx = fmaxf(mx, sa[0][r]);
            if (vis1) {
#pragma unroll
                for (int r = 0; r < 16; ++r) mx = fmaxf(mx, sa[1][r]);
            }
            mx = fmaxf(mx, __shfl_xor(mx, 32));

            bool grow = __any(mx > mrun);
            float mnew = fmaxf(mrun, mx);
            float fsc = 1.f;
            if (grow) {   // strict defer: exact skip when max doesn't grow
                fsc = exp2f_hw(mrun - mnew);
                mrun = mnew;
#pragma unroll
                for (int nd = 0; nd < 2; ++nd)
#pragma unroll
                    for (int j = 0; j < 16; ++j) oacc[nd][j] *= fsc;
            }

            // fused per-n: exp2 -> pack bf16 -> permlane -> PV MFMA
            float rs = 0.f;
            __builtin_amdgcn_s_setprio(1);
#pragma unroll
            for (int n = 0; n < 2; ++n) {
                if (n == 1 && !vis1) break;
                unsigned int wrd[4][2];
#pragma unroll
                for (int u = 0; u < 4; ++u) {
                    float p0 = exp2f_hw(sa[n][4 * u + 0] - mnew);
                    float p1 = exp2f_hw(sa[n][4 * u + 1] - mnew);
                    float p2 = exp2f_hw(sa[n][4 * u + 2] - mnew);
                    float p3 = exp2f_hw(sa[n][4 * u + 3] - mnew);
                    rs += (p0 + p1) + (p2 + p3);
                    asm("v_cvt_pk_bf16_f32 %0, %1, %2" : "=v"(wrd[u][0]) : "v"(p0), "v"(p1));
                    asm("v_cvt_pk_bf16_f32 %0, %1, %2" : "=v"(wrd[u][1]) : "v"(p2), "v"(p3));
                }
#pragma unroll
                for (int half = 0; half < 2; ++half) {
                    int u0 = 2 * half;
                    unsigned int X0 = wrd[u0][0], Y0 = wrd[u0 + 1][0];
                    unsigned int X1 = wrd[u0][1], Y1 = wrd[u0 + 1][1];
                    asm("v_permlane32_swap_b32 %0, %1" : "+v"(X0), "+v"(Y0));
                    asm("v_permlane32_swap_b32 %0, %1" : "+v"(X1), "+v"(Y1));
                    union { unsigned int u[4]; bf16x8 v; } bu;
                    bu.u[0] = X0; bu.u[1] = X1; bu.u[2] = Y0; bu.u[3] = Y1;
                    int kc = 2 * n + half;
#pragma unroll
                    for (int nd = 0; nd < 2; ++nd) {
                        bf16x8 af = *reinterpret_cast<const bf16x8*>(
                            &Vt[(32 * nd + l31) * 64 + (((2 * kc + hi) ^ (l31 & 7)) << 3)]);
                        oacc[nd] = __builtin_amdgcn_mfma_f32_32x32x16_bf16(af, bu.v, oacc[nd], 0, 0, 0);
                    }
                }
            }
            __builtin_amdgcn_s_setprio(0);

            rs += __shfl_xor(rs, 32);
            lrun = lrun * fsc + rs;
        }
        __syncthreads();  // #2: PV reads done; drains K(t+1) prefetch
    }

    // epilogue: divide by row sum, transpose O^T -> O via LDS, coalesced store
    float inv = 1.f / lrun;
    unsigned short* Osm = reinterpret_cast<unsigned short*>(Ksm);
#pragma unroll
    for (int nd = 0; nd < 2; ++nd)
#pragma unroll
        for (int r = 0; r < 16; ++r) {
            int d = 32 * nd + (r & 3) + 8 * (r >> 2) + hi4;
            Osm[w * 2048 + l31 * 64 + ((((d >> 3) ^ (l31 & 7)) << 3) | (d & 7))] =
                f2bf(oacc[nd][r] * inv);
        }
    __syncthreads();
#pragma unroll
    for (int wv = 0; wv < 4; ++wv) {
        int q = tid >> 3, j = tid & 7;
        bf16x8 vv = *reinterpret_cast<const bf16x8*>(Osm + wv * 2048 + q * 64 + ((j ^ (q & 7)) << 3));
        size_t row = (size_t)(b * S_ + brow + wv * 32 + q);
        *reinterpret_cast<bf16x8*>(Ab + row * H_ + h * HD_ + j * 8) = vv;
    }
}

extern "C" void kernel_launch(void* const* d_in, const int* in_sizes, int n_in,
                              void* d_out, int out_size, void* d_ws, size_t ws_size,
                              hipStream_t stream) {
    const float* x  = (const float*)d_in[0];
    const int* amask = (const int*)d_in[1];
    const float* Wq = (const float*)d_in[2];
    const float* Wk = (const float*)d_in[3];
    const float* Wv = (const float*)d_in[4];
    const float* Wo = (const float*)d_in[5];
    const float* bo = (const float*)d_in[6];
    float* out = (float*)d_out;

    const size_t XN = (size_t)B_ * S_ * H_;   // 8388608
    const size_t WN = (size_t)H_ * H_;        // 1048576

    char* ws = (char*)d_ws;
    unsigned short* xb  = (unsigned short*)ws;           ws += XN * 2;
    unsigned short* Wqb = (unsigned short*)ws;           ws += WN * 2;
    unsigned short* Wkb = (unsigned short*)ws;           ws += WN * 2;
    unsigned short* Wvb = (unsigned short*)ws;           ws += WN * 2;
    unsigned short* Wob = (unsigned short*)ws;           ws += WN * 2;
    unsigned short* Qb  = (unsigned short*)ws;           ws += XN * 2;
    unsigned short* Kb  = (unsigned short*)ws;           ws += XN * 2;
    unsigned short* Vb  = (unsigned short*)ws;           ws += XN * 2;
    unsigned short* Ab  = (unsigned short*)ws;           ws += XN * 2;

    cast_f32_bf16<<<(int)(XN / 4 / 256), 256, 0, stream>>>(x, xb, (int)(XN / 4));
    cast_f32_bf16<<<(int)(WN / 4 / 256), 256, 0, stream>>>(Wq, Wqb, (int)(WN / 4));
    cast_f32_bf16<<<(int)(WN / 4 / 256), 256, 0, stream>>>(Wk, Wkb, (int)(WN / 4));
    cast_f32_bf16<<<(int)(WN / 4 / 256), 256, 0, stream>>>(Wv, Wvb, (int)(WN / 4));
    cast_f32_bf16<<<(int)(WN / 4 / 256), 256, 0, stream>>>(Wo, Wob, (int)(WN / 4));

    gemm_qkv<<<dim3(64, 24), 256, 0, stream>>>(xb, Wqb, Wkb, Wvb, Qb, Kb, Vb);
    attn<<<1024, 256, 0, stream>>>(Qb, Kb, Vb, amask, Ab);
    gemm_out<<<dim3(64, 8), 256, 0, stream>>>(Ab, Wob, bo, out);
}

// Round 7
// 184.966 us; speedup vs baseline: 1.8584x; 1.0905x over previous
//
#include <hip/hip_runtime.h>

#define B_ 4
#define S_ 2048
#define H_ 1024
#define NH_ 16
#define HD_ 64
// SCALE * log2(e): QK^T lands in log2 domain; exp -> v_exp_f32 (2^x) directly
#define QSCALE_ 0.1803368801111204f

typedef __attribute__((ext_vector_type(8))) short bf16x8;
typedef __attribute__((ext_vector_type(4))) float f32x4;
typedef __attribute__((ext_vector_type(16))) float f32x16;

__device__ __forceinline__ unsigned short f2bf(float f) {
    unsigned u = __float_as_uint(f);
    unsigned r = (u + 0x7FFFu + ((u >> 16) & 1u)) >> 16;
    return (unsigned short)r;
}
__device__ __forceinline__ float exp2f_hw(float x) { return __builtin_amdgcn_exp2f(x); }

// ---------------- fused cast fp32 -> bf16 for x + 4 weights (1 launch) ----------------
__global__ __launch_bounds__(256) void cast_all(const float* __restrict__ x,
                                                const float* __restrict__ Wq,
                                                const float* __restrict__ Wk,
                                                const float* __restrict__ Wv,
                                                const float* __restrict__ Wo,
                                                unsigned short* __restrict__ xb,
                                                unsigned short* __restrict__ Wqb,
                                                unsigned short* __restrict__ Wkb,
                                                unsigned short* __restrict__ Wvb,
                                                unsigned short* __restrict__ Wob) {
    int bid = blockIdx.x;
    const float* src;
    unsigned short* dst;
    int i;
    if (bid < 8192) {  // x: 8.4M elems / 4 / 256
        src = x; dst = xb; i = bid * 256 + threadIdx.x;
    } else {
        int k = bid - 8192, wsel = k >> 10;
        src = wsel == 0 ? Wq : wsel == 1 ? Wk : wsel == 2 ? Wv : Wo;
        dst = wsel == 0 ? Wqb : wsel == 1 ? Wkb : wsel == 2 ? Wvb : Wob;
        i = (k & 1023) * 256 + threadIdx.x;
    }
    float4 v = reinterpret_cast<const float4*>(src)[i];
    ushort4 o;
    o.x = f2bf(v.x); o.y = f2bf(v.y); o.z = f2bf(v.z); o.w = f2bf(v.w);
    reinterpret_cast<ushort4*>(dst)[i] = o;
}

// ---------------- staging: rows x 128 bytes, XOR slot-swizzled ----------------
__device__ __forceinline__ void stage128_swz(const char* g, int gstride, char* lds, int tid) {
    int wave = tid >> 6, lane = tid & 63;
#pragma unroll
    for (int j = 0; j < 4; ++j) {
        int o = ((wave * 4 + j) * 64 + lane) * 16;
        int r = o >> 7;
        int slot = (o >> 4) & 7;
        const char* src = g + (size_t)r * gstride + ((slot ^ (r & 7)) << 4);
        __builtin_amdgcn_global_load_lds((const __attribute__((address_space(1))) void*)src,
                                         (__attribute__((address_space(3))) void*)(lds + (wave * 4 + j) * 1024),
                                         16, 0, 0);
    }
}
__device__ __forceinline__ void stage64_swz(const char* g, int gstride, char* lds, int tid) {
    int wave = tid >> 6, lane = tid & 63;
#pragma unroll
    for (int j = 0; j < 2; ++j) {
        int o = ((wave * 2 + j) * 64 + lane) * 16;
        int r = o >> 7;
        int slot = (o >> 4) & 7;
        const char* src = g + (size_t)r * gstride + ((slot ^ (r & 7)) << 4);
        __builtin_amdgcn_global_load_lds((const __attribute__((address_space(1))) void*)src,
                                         (__attribute__((address_space(3))) void*)(lds + (wave * 2 + j) * 1024),
                                         16, 0, 0);
    }
}

__device__ __forceinline__ bf16x8 frag_swz(const char* lds, int row, int slot) {
    return *reinterpret_cast<const bf16x8*>(lds + row * 128 + (((slot) ^ (row & 7)) << 4));
}

__device__ __forceinline__ float vmax16(const f32x16& v) {
    float a0 = fmaxf(v[0], v[1]), a1 = fmaxf(v[2], v[3]);
    float a2 = fmaxf(v[4], v[5]), a3 = fmaxf(v[6], v[7]);
    float a4 = fmaxf(v[8], v[9]), a5 = fmaxf(v[10], v[11]);
    float a6 = fmaxf(v[12], v[13]), a7 = fmaxf(v[14], v[15]);
    float b0 = fmaxf(a0, a1), b1 = fmaxf(a2, a3), b2 = fmaxf(a4, a5), b3 = fmaxf(a6, a7);
    return fmaxf(fmaxf(b0, b1), fmaxf(b2, b3));
}

// ---------------- fused QKV projection GEMM: C[M,N] = A[M,K] * W[N,K]^T ----------------
__global__ __launch_bounds__(256) void gemm_qkv(const unsigned short* __restrict__ xb,
                                                const unsigned short* __restrict__ Wq,
                                                const unsigned short* __restrict__ Wk,
                                                const unsigned short* __restrict__ Wv,
                                                unsigned short* __restrict__ Qo,
                                                unsigned short* __restrict__ Ko,
                                                unsigned short* __restrict__ Vo) {
    __shared__ __align__(16) char As[128 * 128];
    __shared__ __align__(16) char Bs[128 * 128];
    int tid = threadIdx.x, lane = tid & 63, wave = tid >> 6;
    int wr = wave >> 1, wc = wave & 1;
    int brow = blockIdx.x * 128;
    int mat = blockIdx.y >> 3;
    int bcol = (blockIdx.y & 7) * 128;
    const unsigned short* W = mat == 0 ? Wq : (mat == 1 ? Wk : Wv);
    unsigned short* O = mat == 0 ? Qo : (mat == 1 ? Ko : Vo);
    float oscale = (mat == 0) ? QSCALE_ : 1.0f;  // fold attn scale + log2e into Q
    f32x4 acc[4][4] = {};
    const char* ga = (const char*)(xb + (size_t)brow * H_);
    const char* gb = (const char*)(W + (size_t)bcol * H_);
    int ro = lane & 15, kg = lane >> 4;
    for (int kt = 0; kt < H_ / 64; ++kt) {
        stage128_swz(ga + kt * 128, H_ * 2, As, tid);
        stage128_swz(gb + kt * 128, H_ * 2, Bs, tid);
        __syncthreads();
#pragma unroll
        for (int kk = 0; kk < 2; ++kk) {
            bf16x8 af[4], bfr[4];
#pragma unroll
            for (int m = 0; m < 4; ++m) af[m] = frag_swz(As, wr * 64 + m * 16 + ro, kk * 4 + kg);
#pragma unroll
            for (int n = 0; n < 4; ++n) bfr[n] = frag_swz(Bs, wc * 64 + n * 16 + ro, kk * 4 + kg);
#pragma unroll
            for (int m = 0; m < 4; ++m)
#pragma unroll
                for (int n = 0; n < 4; ++n)
                    acc[m][n] = __builtin_amdgcn_mfma_f32_16x16x32_bf16(af[m], bfr[n], acc[m][n], 0, 0, 0);
        }
        __syncthreads();
    }
#pragma unroll
    for (int m = 0; m < 4; ++m)
#pragma unroll
        for (int n = 0; n < 4; ++n)
#pragma unroll
            for (int i = 0; i < 4; ++i) {
                int row = brow + wr * 64 + m * 16 + kg * 4 + i;
                int col = bcol + wc * 64 + n * 16 + ro;
                O[(size_t)row * H_ + col] = f2bf(acc[m][n][i] * oscale);
            }
}

// ---------------- output projection GEMM + bias, fp32 out ----------------
__global__ __launch_bounds__(256) void gemm_out(const unsigned short* __restrict__ Ab,
                                                const unsigned short* __restrict__ Wo,
                                                const float* __restrict__ bo,
                                                float* __restrict__ out) {
    __shared__ __align__(16) char As[128 * 128];
    __shared__ __align__(16) char Bs[128 * 128];
    int tid = threadIdx.x, lane = tid & 63, wave = tid >> 6;
    int wr = wave >> 1, wc = wave & 1;
    int brow = blockIdx.x * 128;
    int bcol = blockIdx.y * 128;
    f32x4 acc[4][4] = {};
    const char* ga = (const char*)(Ab + (size_t)brow * H_);
    const char* gb = (const char*)(Wo + (size_t)bcol * H_);
    int ro = lane & 15, kg = lane >> 4;
    for (int kt = 0; kt < H_ / 64; ++kt) {
        stage128_swz(ga + kt * 128, H_ * 2, As, tid);
        stage128_swz(gb + kt * 128, H_ * 2, Bs, tid);
        __syncthreads();
#pragma unroll
        for (int kk = 0; kk < 2; ++kk) {
            bf16x8 af[4], bfr[4];
#pragma unroll
            for (int m = 0; m < 4; ++m) af[m] = frag_swz(As, wr * 64 + m * 16 + ro, kk * 4 + kg);
#pragma unroll
            for (int n = 0; n < 4; ++n) bfr[n] = frag_swz(Bs, wc * 64 + n * 16 + ro, kk * 4 + kg);
#pragma unroll
            for (int m = 0; m < 4; ++m)
#pragma unroll
                for (int n = 0; n < 4; ++n)
                    acc[m][n] = __builtin_amdgcn_mfma_f32_16x16x32_bf16(af[m], bfr[n], acc[m][n], 0, 0, 0);
        }
        __syncthreads();
    }
#pragma unroll
    for (int n = 0; n < 4; ++n) {
        int col = bcol + wc * 64 + n * 16 + ro;
        float bn = bo[col];
#pragma unroll
        for (int m = 0; m < 4; ++m)
#pragma unroll
            for (int i = 0; i < 4; ++i) {
                int row = brow + wr * 64 + m * 16 + kg * 4 + i;
                out[(size_t)row * H_ + col] = acc[m][n][i] + bn;
            }
    }
}

// ---------------- flash attention: swapped QK^T, in-register softmax, KVBLK=64 ----------------
// R4-verified two-barrier schedule (single-barrier variant raced; see journal).
// Per tile: scatter V(t)->Vt, barrier#1, stage K(t+1)+prefetch V(t+1), compute, barrier#2.
// Threshold defer-rescale (log2 THR=10, exact up to final normalize). Cheap scatter addr.
__global__ __launch_bounds__(256) void attn(const unsigned short* __restrict__ Q,
                                            const unsigned short* __restrict__ K,
                                            const unsigned short* __restrict__ V,
                                            const int* __restrict__ amask,
                                            unsigned short* __restrict__ Ab) {
    __shared__ __align__(16) char Ksm[2 * 64 * 128];       // 16KB K dbuf; O-transpose at end
    __shared__ __align__(16) unsigned short Vt[64 * 64];   // 8KB V^T, XOR-swizzled
    __shared__ unsigned char maskc[2048];
    __shared__ unsigned char anyz[32];

    int tid = threadIdx.x, lane = tid & 63, w = tid >> 6;
    int l31 = lane & 31, hi = lane >> 5, hi4 = hi * 4;
    int id = blockIdx.x;
    int qb = 15 - (id >> 6);          // heavy blocks dispatched first
    int bh = id & 63, b = bh >> 4, h = bh & 15;
    int brow = qb * 128;
    int Qwg = brow + w * 32;          // wave's q-base; lane's q-row = Qwg + l31

    // per-lane causal bitmask for the diagonal 32x32 sub-block (kv_local > q_local)
    unsigned cm = 0;
#pragma unroll
    for (int r = 0; r < 16; ++r)
        if (((r & 3) + 8 * (r >> 2) + hi4) > l31) cm |= (1u << r);

    const unsigned short* Qg = Q + (size_t)(b * S_ + Qwg + l31) * H_ + h * HD_;
    const unsigned short* Kg = K + (size_t)b * S_ * H_ + h * HD_;
    const unsigned short* Vg = V + (size_t)b * S_ * H_ + h * HD_;

    // prologue: stage K(0); load V(0); hoist padding mask; load Q frags
    stage64_swz((const char*)Kg, H_ * 2, Ksm, tid);
    bf16x8 vreg[2];
#pragma unroll
    for (int c = 0; c < 2; ++c) {
        int cid = c * 256 + tid;
        int r = cid & 63, d0 = (cid >> 6) * 8;
        vreg[c] = *reinterpret_cast<const bf16x8*>(Vg + (size_t)r * H_ + d0);
    }
    {
        const int4* am4 = reinterpret_cast<const int4*>(amask + b * S_);
        for (int i = tid; i < S_ / 4; i += 256) {
            int4 v = am4[i];
            uchar4 o;
            o.x = (v.x == 0); o.y = (v.y == 0); o.z = (v.z == 0); o.w = (v.w == 0);
            reinterpret_cast<uchar4*>(maskc)[i] = o;
        }
    }
    bf16x8 qf[4];
#pragma unroll
    for (int kk = 0; kk < 4; ++kk)
        qf[kk] = *reinterpret_cast<const bf16x8*>(Qg + kk * 16 + hi * 8);

    __syncthreads();  // prologue: K(0)/V(0) drained; maskc visible
    if (tid < 32) {   // per-64-kv "any masked" byte (visible to all after barrier #1 of t=0)
        const unsigned* mw = reinterpret_cast<const unsigned*>(maskc + tid * 64);
        unsigned o = 0;
#pragma unroll
        for (int i = 0; i < 16; ++i) o |= mw[i];
        anyz[tid] = o ? 1 : 0;
    }

    f32x16 oacc0, oacc1;
#pragma unroll
    for (int j = 0; j < 16; ++j) { oacc0[j] = 0.f; oacc1[j] = 0.f; }
    float mrun = -__builtin_inff(), lrun = 0.f;

    int T = 2 * qb + 2;
    for (int t = 0; t < T; ++t) {
        int kv0 = t * 64;
        const char* Kc = Ksm + (t & 1) * 8192;

        // scatter vreg (= V(t)) -> Vt, cheap factored swizzle addressing
#pragma unroll
        for (int c = 0; c < 2; ++c) {
            int cid = c * 256 + tid;
            int r = cid & 63, d0 = (cid >> 6) * 8;
            unsigned short* vb = Vt + d0 * 64 + (r & 7);
            int rs3 = (r >> 3) << 3;
#pragma unroll
            for (int j = 0; j < 8; ++j)
                vb[j * 64 + (rs3 ^ (j << 3))] = (unsigned short)vreg[c][j];
        }
        __syncthreads();  // #1: Vt visible; K(t) already drained (prev #2 / prologue)

        // stage K(t+1) into other buffer; prefetch V(t+1) into registers
        if (t + 1 < T)
            stage64_swz((const char*)(Kg + (size_t)(kv0 + 64) * H_), H_ * 2,
                        Ksm + ((t + 1) & 1) * 8192, tid);
        {
            int kvn = (t + 1 < T) ? kv0 + 64 : kv0;
#pragma unroll
            for (int c = 0; c < 2; ++c) {
                int cid = c * 256 + tid;
                int r = cid & 63, d0 = (cid >> 6) * 8;
                vreg[c] = *reinterpret_cast<const bf16x8*>(Vg + (size_t)(kvn + r) * H_ + d0);
            }
        }

        int c0 = kv0, c1 = kv0 + 32;
        if (c0 <= Qwg) {             // wave-uniform: any visible work in this tile
            bool vis1 = (c1 <= Qwg);
            f32x16 sa0, sa1;
#pragma unroll
            for (int j = 0; j < 16; ++j) { sa0[j] = 0.f; sa1[j] = 0.f; }

            __builtin_amdgcn_s_setprio(1);
#pragma unroll
            for (int kk = 0; kk < 4; ++kk) {
                bf16x8 kf0 = frag_swz(Kc, l31, 2 * kk + hi);
                sa0 = __builtin_amdgcn_mfma_f32_32x32x16_bf16(kf0, qf[kk], sa0, 0, 0, 0);
                if (vis1) {
                    bf16x8 kf1 = frag_swz(Kc, 32 + l31, 2 * kk + hi);
                    sa1 = __builtin_amdgcn_mfma_f32_32x32x16_bf16(kf1, qf[kk], sa1, 0, 0, 0);
                }
            }
            __builtin_amdgcn_s_setprio(0);

            // causal: diagonal sub-block at most once per wave
            if (c0 == Qwg) {
#pragma unroll
                for (int r = 0; r < 16; ++r) sa0[r] = (cm & (1u << r)) ? -1e9f : sa0[r];
            }
            if (vis1 && c1 == Qwg) {
#pragma unroll
                for (int r = 0; r < 16; ++r) sa1[r] = (cm & (1u << r)) ? -1e9f : sa1[r];
            }
            // padding mask (skipped when this 64-kv group is all-ones)
            if (anyz[t]) {
#pragma unroll
                for (int u = 0; u < 4; ++u) {
                    uchar4 mk = *reinterpret_cast<const uchar4*>(maskc + kv0 + 8 * u + hi4);
                    if (mk.x) sa0[4 * u + 0] = -1e9f;
                    if (mk.y) sa0[4 * u + 1] = -1e9f;
                    if (mk.z) sa0[4 * u + 2] = -1e9f;
                    if (mk.w) sa0[4 * u + 3] = -1e9f;
                }
                if (vis1) {
#pragma unroll
                    for (int u = 0; u < 4; ++u) {
                        uchar4 mk = *reinterpret_cast<const uchar4*>(maskc + kv0 + 32 + 8 * u + hi4);
                        if (mk.x) sa1[4 * u + 0] = -1e9f;
                        if (mk.y) sa1[4 * u + 1] = -1e9f;
                        if (mk.z) sa1[4 * u + 2] = -1e9f;
                        if (mk.w) sa1[4 * u + 3] = -1e9f;
                    }
                }
            }

            // tree row-max; cross-half via shfl
            float mx = vmax16(sa0);
            if (vis1) mx = fmaxf(mx, vmax16(sa1));
            mx = fmaxf(mx, __shfl_xor(mx, 32));

            // threshold defer-rescale: only pay the O-pass when max grows by >10 (log2)
            if (__any(mx > mrun + 10.f)) {
                float mnew = fmaxf(mrun, mx);
                float fsc = exp2f_hw(mrun - mnew);
                mrun = mnew;
                lrun *= fsc;
#pragma unroll
                for (int j = 0; j < 16; ++j) { oacc0[j] *= fsc; oacc1[j] *= fsc; }
            }

            // fused per-n: exp2 -> pack bf16 -> permlane -> PV MFMA
            float rs = 0.f;
            __builtin_amdgcn_s_setprio(1);
#pragma unroll
            for (int n = 0; n < 2; ++n) {
                if (n == 1 && !vis1) break;
                const f32x16& sa = (n == 0) ? sa0 : sa1;
                unsigned int wrd[4][2];
#pragma unroll
                for (int u = 0; u < 4; ++u) {
                    float p0 = exp2f_hw(sa[4 * u + 0] - mrun);
                    float p1 = exp2f_hw(sa[4 * u + 1] - mrun);
                    float p2 = exp2f_hw(sa[4 * u + 2] - mrun);
                    float p3 = exp2f_hw(sa[4 * u + 3] - mrun);
                    rs += (p0 + p1) + (p2 + p3);
                    asm("v_cvt_pk_bf16_f32 %0, %1, %2" : "=v"(wrd[u][0]) : "v"(p0), "v"(p1));
                    asm("v_cvt_pk_bf16_f32 %0, %1, %2" : "=v"(wrd[u][1]) : "v"(p2), "v"(p3));
                }
#pragma unroll
                for (int half = 0; half < 2; ++half) {
                    int u0 = 2 * half;
                    unsigned int X0 = wrd[u0][0], Y0 = wrd[u0 + 1][0];
                    unsigned int X1 = wrd[u0][1], Y1 = wrd[u0 + 1][1];
                    asm("v_permlane32_swap_b32 %0, %1" : "+v"(X0), "+v"(Y0));
                    asm("v_permlane32_swap_b32 %0, %1" : "+v"(X1), "+v"(Y1));
                    union { unsigned int u[4]; bf16x8 v; } bu;
                    bu.u[0] = X0; bu.u[1] = X1; bu.u[2] = Y0; bu.u[3] = Y1;
                    int kc = 2 * n + half;
                    bf16x8 af0 = *reinterpret_cast<const bf16x8*>(
                        &Vt[(l31) * 64 + (((2 * kc + hi) ^ (l31 & 7)) << 3)]);
                    oacc0 = __builtin_amdgcn_mfma_f32_32x32x16_bf16(af0, bu.v, oacc0, 0, 0, 0);
                    bf16x8 af1 = *reinterpret_cast<const bf16x8*>(
                        &Vt[(32 + l31) * 64 + (((2 * kc + hi) ^ (l31 & 7)) << 3)]);
                    oacc1 = __builtin_amdgcn_mfma_f32_32x32x16_bf16(af1, bu.v, oacc1, 0, 0, 0);
                }
            }
            __builtin_amdgcn_s_setprio(0);

            rs += __shfl_xor(rs, 32);
            lrun += rs;
        }
        __syncthreads();  // #2: Vt reads done; K(t+1)/V(t+1) prefetch drained
    }

    // epilogue: divide by row sum, transpose O^T -> O via LDS, coalesced store
    float inv = 1.f / lrun;
    unsigned short* Osm = reinterpret_cast<unsigned short*>(Ksm);
#pragma unroll
    for (int r = 0; r < 16; ++r) {
        int d = (r & 3) + 8 * (r >> 2) + hi4;
        Osm[w * 2048 + l31 * 64 + ((((d >> 3) ^ (l31 & 7)) << 3) | (d & 7))] = f2bf(oacc0[r] * inv);
        int d1 = d + 32;
        Osm[w * 2048 + l31 * 64 + ((((d1 >> 3) ^ (l31 & 7)) << 3) | (d1 & 7))] = f2bf(oacc1[r] * inv);
    }
    __syncthreads();
#pragma unroll
    for (int wv = 0; wv < 4; ++wv) {
        int q = tid >> 3, j = tid & 7;
        bf16x8 vv = *reinterpret_cast<const bf16x8*>(Osm + wv * 2048 + q * 64 + ((j ^ (q & 7)) << 3));
        size_t row = (size_t)(b * S_ + brow + wv * 32 + q);
        *reinterpret_cast<bf16x8*>(Ab + row * H_ + h * HD_ + j * 8) = vv;
    }
}

extern "C" void kernel_launch(void* const* d_in, const int* in_sizes, int n_in,
                              void* d_out, int out_size, void* d_ws, size_t ws_size,
                              hipStream_t stream) {
    const float* x  = (const float*)d_in[0];
    const int* amask = (const int*)d_in[1];
    const float* Wq = (const float*)d_in[2];
    const float* Wk = (const float*)d_in[3];
    const float* Wv = (const float*)d_in[4];
    const float* Wo = (const float*)d_in[5];
    const float* bo = (const float*)d_in[6];
    float* out = (float*)d_out;

    const size_t XN = (size_t)B_ * S_ * H_;   // 8388608
    const size_t WN = (size_t)H_ * H_;        // 1048576

    char* ws = (char*)d_ws;
    unsigned short* xb  = (unsigned short*)ws;           ws += XN * 2;
    unsigned short* Wqb = (unsigned short*)ws;           ws += WN * 2;
    unsigned short* Wkb = (unsigned short*)ws;           ws += WN * 2;
    unsigned short* Wvb = (unsigned short*)ws;           ws += WN * 2;
    unsigned short* Wob = (unsigned short*)ws;           ws += WN * 2;
    unsigned short* Qb  = (unsigned short*)ws;           ws += XN * 2;
    unsigned short* Kb  = (unsigned short*)ws;           ws += XN * 2;
    unsigned short* Vb  = (unsigned short*)ws;           ws += XN * 2;
    unsigned short* Ab  = (unsigned short*)ws;           ws += XN * 2;

    cast_all<<<12288, 256, 0, stream>>>(x, Wq, Wk, Wv, Wo, xb, Wqb, Wkb, Wvb, Wob);
    gemm_qkv<<<dim3(64, 24), 256, 0, stream>>>(xb, Wqb, Wkb, Wvb, Qb, Kb, Vb);
    attn<<<1024, 256, 0, stream>>>(Qb, Kb, Vb, amask, Ab);
    gemm_out<<<dim3(64, 8), 256, 0, stream>>>(Ab, Wob, bo, out);
}

// Round 8
// 166.761 us; speedup vs baseline: 2.0613x; 1.1092x over previous
//
#include <hip/hip_runtime.h>

#define B_ 4
#define S_ 2048
#define H_ 1024
#define NH_ 16
#define HD_ 64
// SCALE * log2(e): QK^T lands in log2 domain; exp -> v_exp_f32 (2^x) directly
#define QSCALE_ 0.1803368801111204f

typedef __attribute__((ext_vector_type(8))) short bf16x8;
typedef __attribute__((ext_vector_type(4))) float f32x4;
typedef __attribute__((ext_vector_type(16))) float f32x16;

__device__ __forceinline__ unsigned short f2bf(float f) {
    unsigned u = __float_as_uint(f);
    unsigned r = (u + 0x7FFFu + ((u >> 16) & 1u)) >> 16;
    return (unsigned short)r;
}
__device__ __forceinline__ float exp2f_hw(float x) { return __builtin_amdgcn_exp2f(x); }

// ---------------- fused cast fp32 -> bf16 for x + 4 weights (1 launch) ----------------
__global__ __launch_bounds__(256) void cast_all(const float* __restrict__ x,
                                                const float* __restrict__ Wq,
                                                const float* __restrict__ Wk,
                                                const float* __restrict__ Wv,
                                                const float* __restrict__ Wo,
                                                unsigned short* __restrict__ xb,
                                                unsigned short* __restrict__ Wqb,
                                                unsigned short* __restrict__ Wkb,
                                                unsigned short* __restrict__ Wvb,
                                                unsigned short* __restrict__ Wob) {
    int bid = blockIdx.x;
    const float* src;
    unsigned short* dst;
    int i;
    if (bid < 8192) {  // x: 8.4M elems / 4 / 256
        src = x; dst = xb; i = bid * 256 + threadIdx.x;
    } else {
        int k = bid - 8192, wsel = k >> 10;
        src = wsel == 0 ? Wq : wsel == 1 ? Wk : wsel == 2 ? Wv : Wo;
        dst = wsel == 0 ? Wqb : wsel == 1 ? Wkb : wsel == 2 ? Wvb : Wob;
        i = (k & 1023) * 256 + threadIdx.x;
    }
    float4 v = reinterpret_cast<const float4*>(src)[i];
    ushort4 o;
    o.x = f2bf(v.x); o.y = f2bf(v.y); o.z = f2bf(v.z); o.w = f2bf(v.w);
    reinterpret_cast<ushort4*>(dst)[i] = o;
}

// ---------------- staging: rows x 128 bytes, XOR slot-swizzled ----------------
// 256-thread (4-wave) version: each wave stages 4KB (32 rows)
__device__ __forceinline__ void stage128_swz(const char* g, int gstride, char* lds, int tid) {
    int wave = tid >> 6, lane = tid & 63;
#pragma unroll
    for (int j = 0; j < 4; ++j) {
        int o = ((wave * 4 + j) * 64 + lane) * 16;
        int r = o >> 7;
        int slot = (o >> 4) & 7;
        const char* src = g + (size_t)r * gstride + ((slot ^ (r & 7)) << 4);
        __builtin_amdgcn_global_load_lds((const __attribute__((address_space(1))) void*)src,
                                         (__attribute__((address_space(3))) void*)(lds + (wave * 4 + j) * 1024),
                                         16, 0, 0);
    }
}
// 512-thread (8-wave) version: each wave stages 1KB (8 rows of a 64x128B tile)
__device__ __forceinline__ void stage64_swz8(const char* g, int gstride, char* lds, int tid) {
    int wave = tid >> 6, lane = tid & 63;
    int o = (wave * 64 + lane) * 16;
    int r = o >> 7;                 // wave*8 + lane>>3
    int slot = (o >> 4) & 7;        // lane&7
    const char* src = g + (size_t)r * gstride + ((slot ^ (r & 7)) << 4);
    __builtin_amdgcn_global_load_lds((const __attribute__((address_space(1))) void*)src,
                                     (__attribute__((address_space(3))) void*)(lds + wave * 1024 + lane * 16),
                                     16, 0, 0);
}

__device__ __forceinline__ bf16x8 frag_swz(const char* lds, int row, int slot) {
    return *reinterpret_cast<const bf16x8*>(lds + row * 128 + (((slot) ^ (row & 7)) << 4));
}

__device__ __forceinline__ float vmax16(const f32x16& v) {
    float a0 = fmaxf(v[0], v[1]), a1 = fmaxf(v[2], v[3]);
    float a2 = fmaxf(v[4], v[5]), a3 = fmaxf(v[6], v[7]);
    float a4 = fmaxf(v[8], v[9]), a5 = fmaxf(v[10], v[11]);
    float a6 = fmaxf(v[12], v[13]), a7 = fmaxf(v[14], v[15]);
    float b0 = fmaxf(a0, a1), b1 = fmaxf(a2, a3), b2 = fmaxf(a4, a5), b3 = fmaxf(a6, a7);
    return fmaxf(fmaxf(b0, b1), fmaxf(b2, b3));
}

// ---------------- fused QKV projection GEMM: C[M,N] = A[M,K] * W[N,K]^T ----------------
// 1-D grid 1536, XCD-clustered: each XCD owns 8 consecutive A row-panels (2MB, L2-resident)
// across all 24 (mat,col) tiles -> A staging hits its own L2.
__global__ __launch_bounds__(256) void gemm_qkv(const unsigned short* __restrict__ xb,
                                                const unsigned short* __restrict__ Wq,
                                                const unsigned short* __restrict__ Wk,
                                                const unsigned short* __restrict__ Wv,
                                                unsigned short* __restrict__ Qo,
                                                unsigned short* __restrict__ Ko,
                                                unsigned short* __restrict__ Vo) {
    __shared__ __align__(16) char As[128 * 128];
    __shared__ __align__(16) char Bs[128 * 128];
    int tid = threadIdx.x, lane = tid & 63, wave = tid >> 6;
    int wr = wave >> 1, wc = wave & 1;
    int bid = blockIdx.x;
    int t = (bid & 7) * 192 + (bid >> 3);   // XCD cluster: t row-panel-major
    int xrow = t / 24;
    int ym = t - xrow * 24;
    int brow = xrow * 128;
    int mat = ym >> 3;
    int bcol = (ym & 7) * 128;
    const unsigned short* W = mat == 0 ? Wq : (mat == 1 ? Wk : Wv);
    unsigned short* O = mat == 0 ? Qo : (mat == 1 ? Ko : Vo);
    float oscale = (mat == 0) ? QSCALE_ : 1.0f;  // fold attn scale + log2e into Q
    f32x4 acc[4][4] = {};
    const char* ga = (const char*)(xb + (size_t)brow * H_);
    const char* gb = (const char*)(W + (size_t)bcol * H_);
    int ro = lane & 15, kg = lane >> 4;
    for (int kt = 0; kt < H_ / 64; ++kt) {
        stage128_swz(ga + kt * 128, H_ * 2, As, tid);
        stage128_swz(gb + kt * 128, H_ * 2, Bs, tid);
        __syncthreads();
#pragma unroll
        for (int kk = 0; kk < 2; ++kk) {
            bf16x8 af[4], bfr[4];
#pragma unroll
            for (int m = 0; m < 4; ++m) af[m] = frag_swz(As, wr * 64 + m * 16 + ro, kk * 4 + kg);
#pragma unroll
            for (int n = 0; n < 4; ++n) bfr[n] = frag_swz(Bs, wc * 64 + n * 16 + ro, kk * 4 + kg);
#pragma unroll
            for (int m = 0; m < 4; ++m)
#pragma unroll
                for (int n = 0; n < 4; ++n)
                    acc[m][n] = __builtin_amdgcn_mfma_f32_16x16x32_bf16(af[m], bfr[n], acc[m][n], 0, 0, 0);
        }
        __syncthreads();
    }
#pragma unroll
    for (int m = 0; m < 4; ++m)
#pragma unroll
        for (int n = 0; n < 4; ++n)
#pragma unroll
            for (int i = 0; i < 4; ++i) {
                int row = brow + wr * 64 + m * 16 + kg * 4 + i;
                int col = bcol + wc * 64 + n * 16 + ro;
                O[(size_t)row * H_ + col] = f2bf(acc[m][n][i] * oscale);
            }
}

// ---------------- output projection GEMM + bias, fp32 out (XCD-clustered) ----------------
__global__ __launch_bounds__(256) void gemm_out(const unsigned short* __restrict__ Ab,
                                                const unsigned short* __restrict__ Wo,
                                                const float* __restrict__ bo,
                                                float* __restrict__ out) {
    __shared__ __align__(16) char As[128 * 128];
    __shared__ __align__(16) char Bs[128 * 128];
    int tid = threadIdx.x, lane = tid & 63, wave = tid >> 6;
    int wr = wave >> 1, wc = wave & 1;
    int bid = blockIdx.x;
    int t = (bid & 7) * 64 + (bid >> 3);
    int brow = (t >> 3) * 128;
    int bcol = (t & 7) * 128;
    f32x4 acc[4][4] = {};
    const char* ga = (const char*)(Ab + (size_t)brow * H_);
    const char* gb = (const char*)(Wo + (size_t)bcol * H_);
    int ro = lane & 15, kg = lane >> 4;
    for (int kt = 0; kt < H_ / 64; ++kt) {
        stage128_swz(ga + kt * 128, H_ * 2, As, tid);
        stage128_swz(gb + kt * 128, H_ * 2, Bs, tid);
        __syncthreads();
#pragma unroll
        for (int kk = 0; kk < 2; ++kk) {
            bf16x8 af[4], bfr[4];
#pragma unroll
            for (int m = 0; m < 4; ++m) af[m] = frag_swz(As, wr * 64 + m * 16 + ro, kk * 4 + kg);
#pragma unroll
            for (int n = 0; n < 4; ++n) bfr[n] = frag_swz(Bs, wc * 64 + n * 16 + ro, kk * 4 + kg);
#pragma unroll
            for (int m = 0; m < 4; ++m)
#pragma unroll
                for (int n = 0; n < 4; ++n)
                    acc[m][n] = __builtin_amdgcn_mfma_f32_16x16x32_bf16(af[m], bfr[n], acc[m][n], 0, 0, 0);
        }
        __syncthreads();
    }
#pragma unroll
    for (int n = 0; n < 4; ++n) {
        int col = bcol + wc * 64 + n * 16 + ro;
        float bn = bo[col];
#pragma unroll
        for (int m = 0; m < 4; ++m)
#pragma unroll
            for (int i = 0; i < 4; ++i) {
                int row = brow + wr * 64 + m * 16 + kg * 4 + i;
                out[(size_t)row * H_ + col] = acc[m][n][i] + bn;
            }
    }
}

// ---------------- flash attention: 8 waves x 32 q-rows (QBLK=256), KVBLK=64 ----------------
// R7-verified two-barrier skeleton; staging split across 8 waves (half cost/wave).
// grid: 512 blocks; qb permuted so co-resident blocks' work sums are equal.
__global__ __launch_bounds__(512) void attn(const unsigned short* __restrict__ Q,
                                            const unsigned short* __restrict__ K,
                                            const unsigned short* __restrict__ V,
                                            const int* __restrict__ amask,
                                            unsigned short* __restrict__ Ab) {
    __shared__ __align__(16) char lds[32768];
    char* Ksm = lds;                                             // 16KB K dbuf
    unsigned short* Vt = (unsigned short*)(lds + 16384);         // 8KB V^T swizzled
    unsigned char* maskc = (unsigned char*)(lds + 24576);        // 2KB
    unsigned char* anyz = (unsigned char*)(lds + 26624);         // 32B
    // epilogue reuses all 32KB as O-transpose buffer

    int tid = threadIdx.x, lane = tid & 63, w = tid >> 6;        // w 0..7
    int l31 = lane & 31, hi = lane >> 5, hi4 = hi * 4;
    int id = blockIdx.x;
    int g = id >> 6;
    int qb = (g < 4) ? (7 - 2 * g) : (2 * g - 8);   // balanced pairs: qb(g)+qb(g+4)=7, heavy first
    int bh = id & 63, b = bh >> 4, h = bh & 15;
    int brow = qb * 256;
    int Qwg = brow + w * 32;          // wave's q-base; lane's q-row = Qwg + l31

    // per-lane causal bitmask for the diagonal 32x32 sub-block (kv_local > q_local)
    unsigned cm = 0;
#pragma unroll
    for (int r = 0; r < 16; ++r)
        if (((r & 3) + 8 * (r >> 2) + hi4) > l31) cm |= (1u << r);

    const unsigned short* Qg = Q + (size_t)(b * S_ + Qwg + l31) * H_ + h * HD_;
    const unsigned short* Kg = K + (size_t)b * S_ * H_ + h * HD_;
    const unsigned short* Vg = V + (size_t)b * S_ * H_ + h * HD_;

    // prologue: stage K(0); load V(0); hoist padding mask; load Q frags
    stage64_swz8((const char*)Kg, H_ * 2, Ksm, tid);
    int vr = tid & 63, vd0 = (tid >> 6) * 8;    // each thread owns (kv=vr, d=vd0..vd0+7)
    bf16x8 vreg = *reinterpret_cast<const bf16x8*>(Vg + (size_t)vr * H_ + vd0);
    {
        const int4* am4 = reinterpret_cast<const int4*>(amask + b * S_);
        int i = tid;
        if (i < S_ / 4) {
            int4 v = am4[i];
            uchar4 o;
            o.x = (v.x == 0); o.y = (v.y == 0); o.z = (v.z == 0); o.w = (v.w == 0);
            reinterpret_cast<uchar4*>(maskc)[i] = o;
        }
    }
    bf16x8 qf[4];
#pragma unroll
    for (int kk = 0; kk < 4; ++kk)
        qf[kk] = *reinterpret_cast<const bf16x8*>(Qg + kk * 16 + hi * 8);

    __syncthreads();  // prologue: K(0)/V(0) drained; maskc visible
    if (tid < 32) {   // per-64-kv "any masked" byte (covered by barrier #1 of t=0)
        const unsigned* mw = reinterpret_cast<const unsigned*>(maskc + tid * 64);
        unsigned o = 0;
#pragma unroll
        for (int i = 0; i < 16; ++i) o |= mw[i];
        anyz[tid] = o ? 1 : 0;
    }

    f32x16 oacc0, oacc1;
#pragma unroll
    for (int j = 0; j < 16; ++j) { oacc0[j] = 0.f; oacc1[j] = 0.f; }
    float mrun = -__builtin_inff(), lrun = 0.f;

    int T = 4 * qb + 4;
    for (int t = 0; t < T; ++t) {
        int kv0 = t * 64;
        const char* Kc = Ksm + (t & 1) * 8192;

        // scatter vreg (= V(t)) -> Vt, cheap factored swizzle addressing
        {
            unsigned short* vb = Vt + vd0 * 64 + (vr & 7);
            int rs3 = (vr >> 3) << 3;
#pragma unroll
            for (int j = 0; j < 8; ++j)
                vb[j * 64 + (rs3 ^ (j << 3))] = (unsigned short)vreg[j];
        }
        __syncthreads();  // #1: Vt visible; K(t) already drained (prev #2 / prologue)

        // stage K(t+1) into other buffer; prefetch V(t+1) into registers
        if (t + 1 < T)
            stage64_swz8((const char*)(Kg + (size_t)(kv0 + 64) * H_), H_ * 2,
                         Ksm + ((t + 1) & 1) * 8192, tid);
        {
            int kvn = (t + 1 < T) ? kv0 + 64 : kv0;
            vreg = *reinterpret_cast<const bf16x8*>(Vg + (size_t)(kvn + vr) * H_ + vd0);
        }

        int c0 = kv0, c1 = kv0 + 32;
        if (c0 <= Qwg) {             // wave-uniform: any visible work in this tile
            bool vis1 = (c1 <= Qwg);
            f32x16 sa0, sa1;
#pragma unroll
            for (int j = 0; j < 16; ++j) { sa0[j] = 0.f; sa1[j] = 0.f; }

            __builtin_amdgcn_s_setprio(1);
#pragma unroll
            for (int kk = 0; kk < 4; ++kk) {
                bf16x8 kf0 = frag_swz(Kc, l31, 2 * kk + hi);
                sa0 = __builtin_amdgcn_mfma_f32_32x32x16_bf16(kf0, qf[kk], sa0, 0, 0, 0);
                if (vis1) {
                    bf16x8 kf1 = frag_swz(Kc, 32 + l31, 2 * kk + hi);
                    sa1 = __builtin_amdgcn_mfma_f32_32x32x16_bf16(kf1, qf[kk], sa1, 0, 0, 0);
                }
            }
            __builtin_amdgcn_s_setprio(0);

            // causal: diagonal sub-block at most once per wave
            if (c0 == Qwg) {
#pragma unroll
                for (int r = 0; r < 16; ++r) sa0[r] = (cm & (1u << r)) ? -1e9f : sa0[r];
            }
            if (vis1 && c1 == Qwg) {
#pragma unroll
                for (int r = 0; r < 16; ++r) sa1[r] = (cm & (1u << r)) ? -1e9f : sa1[r];
            }
            // padding mask (skipped when this 64-kv group is all-ones)
            if (anyz[t]) {
#pragma unroll
                for (int u = 0; u < 4; ++u) {
                    uchar4 mk = *reinterpret_cast<const uchar4*>(maskc + kv0 + 8 * u + hi4);
                    if (mk.x) sa0[4 * u + 0] = -1e9f;
                    if (mk.y) sa0[4 * u + 1] = -1e9f;
                    if (mk.z) sa0[4 * u + 2] = -1e9f;
                    if (mk.w) sa0[4 * u + 3] = -1e9f;
                }
                if (vis1) {
#pragma unroll
                    for (int u = 0; u < 4; ++u) {
                        uchar4 mk = *reinterpret_cast<const uchar4*>(maskc + kv0 + 32 + 8 * u + hi4);
                        if (mk.x) sa1[4 * u + 0] = -1e9f;
                        if (mk.y) sa1[4 * u + 1] = -1e9f;
                        if (mk.z) sa1[4 * u + 2] = -1e9f;
                        if (mk.w) sa1[4 * u + 3] = -1e9f;
                    }
                }
            }

            // tree row-max; cross-half via shfl
            float mx = vmax16(sa0);
            if (vis1) mx = fmaxf(mx, vmax16(sa1));
            mx = fmaxf(mx, __shfl_xor(mx, 32));

            // threshold defer-rescale: only pay the O-pass when max grows by >10 (log2)
            if (__any(mx > mrun + 10.f)) {
                float mnew = fmaxf(mrun, mx);
                float fsc = exp2f_hw(mrun - mnew);
                mrun = mnew;
                lrun *= fsc;
#pragma unroll
                for (int j = 0; j < 16; ++j) { oacc0[j] *= fsc; oacc1[j] *= fsc; }
            }

            // fused per-n: exp2 -> pack bf16 -> permlane -> PV MFMA
            float rs = 0.f;
            __builtin_amdgcn_s_setprio(1);
#pragma unroll
            for (int n = 0; n < 2; ++n) {
                if (n == 1 && !vis1) break;
                const f32x16& sa = (n == 0) ? sa0 : sa1;
                unsigned int wrd[4][2];
#pragma unroll
                for (int u = 0; u < 4; ++u) {
                    float p0 = exp2f_hw(sa[4 * u + 0] - mrun);
                    float p1 = exp2f_hw(sa[4 * u + 1] - mrun);
                    float p2 = exp2f_hw(sa[4 * u + 2] - mrun);
                    float p3 = exp2f_hw(sa[4 * u + 3] - mrun);
                    rs += (p0 + p1) + (p2 + p3);
                    asm("v_cvt_pk_bf16_f32 %0, %1, %2" : "=v"(wrd[u][0]) : "v"(p0), "v"(p1));
                    asm("v_cvt_pk_bf16_f32 %0, %1, %2" : "=v"(wrd[u][1]) : "v"(p2), "v"(p3));
                }
#pragma unroll
                for (int half = 0; half < 2; ++half) {
                    int u0 = 2 * half;
                    unsigned int X0 = wrd[u0][0], Y0 = wrd[u0 + 1][0];
                    unsigned int X1 = wrd[u0][1], Y1 = wrd[u0 + 1][1];
                    asm("v_permlane32_swap_b32 %0, %1" : "+v"(X0), "+v"(Y0));
                    asm("v_permlane32_swap_b32 %0, %1" : "+v"(X1), "+v"(Y1));
                    union { unsigned int u[4]; bf16x8 v; } bu;
                    bu.u[0] = X0; bu.u[1] = X1; bu.u[2] = Y0; bu.u[3] = Y1;
                    int kc = 2 * n + half;
                    bf16x8 af0 = *reinterpret_cast<const bf16x8*>(
                        &Vt[(l31) * 64 + (((2 * kc + hi) ^ (l31 & 7)) << 3)]);
                    oacc0 = __builtin_amdgcn_mfma_f32_32x32x16_bf16(af0, bu.v, oacc0, 0, 0, 0);
                    bf16x8 af1 = *reinterpret_cast<const bf16x8*>(
                        &Vt[(32 + l31) * 64 + (((2 * kc + hi) ^ (l31 & 7)) << 3)]);
                    oacc1 = __builtin_amdgcn_mfma_f32_32x32x16_bf16(af1, bu.v, oacc1, 0, 0, 0);
                }
            }
            __builtin_amdgcn_s_setprio(0);

            rs += __shfl_xor(rs, 32);
            lrun += rs;
        }
        __syncthreads();  // #2: Vt reads done; K(t+1)/V(t+1) prefetch drained
    }

    // epilogue: divide by row sum, transpose O^T -> O via LDS (reuse all 32KB), store
    float inv = 1.f / lrun;
    unsigned short* Osm = reinterpret_cast<unsigned short*>(lds);
#pragma unroll
    for (int r = 0; r < 16; ++r) {
        int d = (r & 3) + 8 * (r >> 2) + hi4;
        Osm[w * 2048 + l31 * 64 + ((((d >> 3) ^ (l31 & 7)) << 3) | (d & 7))] = f2bf(oacc0[r] * inv);
        int d1 = d + 32;
        Osm[w * 2048 + l31 * 64 + ((((d1 >> 3) ^ (l31 & 7)) << 3) | (d1 & 7))] = f2bf(oacc1[r] * inv);
    }
    __syncthreads();
#pragma unroll
    for (int wv = 0; wv < 4; ++wv) {
        int q = tid >> 3, j = tid & 7;      // q 0..63
        int row = wv * 64 + q;              // 0..255
        bf16x8 vv = *reinterpret_cast<const bf16x8*>(
            Osm + (row >> 5) * 2048 + (row & 31) * 64 + ((j ^ (row & 7)) << 3));
        size_t grow = (size_t)(b * S_ + brow + row);
        *reinterpret_cast<bf16x8*>(Ab + grow * H_ + h * HD_ + j * 8) = vv;
    }
}

extern "C" void kernel_launch(void* const* d_in, const int* in_sizes, int n_in,
                              void* d_out, int out_size, void* d_ws, size_t ws_size,
                              hipStream_t stream) {
    const float* x  = (const float*)d_in[0];
    const int* amask = (const int*)d_in[1];
    const float* Wq = (const float*)d_in[2];
    const float* Wk = (const float*)d_in[3];
    const float* Wv = (const float*)d_in[4];
    const float* Wo = (const float*)d_in[5];
    const float* bo = (const float*)d_in[6];
    float* out = (float*)d_out;

    const size_t XN = (size_t)B_ * S_ * H_;   // 8388608
    const size_t WN = (size_t)H_ * H_;        // 1048576

    char* ws = (char*)d_ws;
    unsigned short* xb  = (unsigned short*)ws;           ws += XN * 2;
    unsigned short* Wqb = (unsigned short*)ws;           ws += WN * 2;
    unsigned short* Wkb = (unsigned short*)ws;           ws += WN * 2;
    unsigned short* Wvb = (unsigned short*)ws;           ws += WN * 2;
    unsigned short* Wob = (unsigned short*)ws;           ws += WN * 2;
    unsigned short* Qb  = (unsigned short*)ws;           ws += XN * 2;
    unsigned short* Kb  = (unsigned short*)ws;           ws += XN * 2;
    unsigned short* Vb  = (unsigned short*)ws;           ws += XN * 2;
    unsigned short* Ab  = (unsigned short*)ws;           ws += XN * 2;

    cast_all<<<12288, 256, 0, stream>>>(x, Wq, Wk, Wv, Wo, xb, Wqb, Wkb, Wvb, Wob);
    gemm_qkv<<<1536, 256, 0, stream>>>(xb, Wqb, Wkb, Wvb, Qb, Kb, Vb);
    attn<<<512, 512, 0, stream>>>(Qb, Kb, Vb, amask, Ab);
    gemm_out<<<512, 256, 0, stream>>>(Ab, Wob, bo, out);
}

// Round 9
// 164.781 us; speedup vs baseline: 2.0861x; 1.0120x over previous
//
#include <hip/hip_runtime.h>

#define B_ 4
#define S_ 2048
#define H_ 1024
#define NH_ 16
#define HD_ 64
// SCALE * log2(e): QK^T lands in log2 domain; exp -> v_exp_f32 (2^x) directly
#define QSCALE_ 0.1803368801111204f

typedef __attribute__((ext_vector_type(8))) short bf16x8;
typedef __attribute__((ext_vector_type(4))) float f32x4;
typedef __attribute__((ext_vector_type(16))) float f32x16;

__device__ __forceinline__ unsigned short f2bf(float f) {
    unsigned u = __float_as_uint(f);
    unsigned r = (u + 0x7FFFu + ((u >> 16) & 1u)) >> 16;
    return (unsigned short)r;
}
__device__ __forceinline__ float exp2f_hw(float x) { return __builtin_amdgcn_exp2f(x); }

// ---------------- fused cast fp32 -> bf16 for x + 4 weights (1 launch) ----------------
__global__ __launch_bounds__(256) void cast_all(const float* __restrict__ x,
                                                const float* __restrict__ Wq,
                                                const float* __restrict__ Wk,
                                                const float* __restrict__ Wv,
                                                const float* __restrict__ Wo,
                                                unsigned short* __restrict__ xb,
                                                unsigned short* __restrict__ Wqb,
                                                unsigned short* __restrict__ Wkb,
                                                unsigned short* __restrict__ Wvb,
                                                unsigned short* __restrict__ Wob) {
    int bid = blockIdx.x;
    const float* src;
    unsigned short* dst;
    int i;
    if (bid < 8192) {  // x: 8.4M elems / 4 / 256
        src = x; dst = xb; i = bid * 256 + threadIdx.x;
    } else {
        int k = bid - 8192, wsel = k >> 10;
        src = wsel == 0 ? Wq : wsel == 1 ? Wk : wsel == 2 ? Wv : Wo;
        dst = wsel == 0 ? Wqb : wsel == 1 ? Wkb : wsel == 2 ? Wvb : Wob;
        i = (k & 1023) * 256 + threadIdx.x;
    }
    float4 v = reinterpret_cast<const float4*>(src)[i];
    ushort4 o;
    o.x = f2bf(v.x); o.y = f2bf(v.y); o.z = f2bf(v.z); o.w = f2bf(v.w);
    reinterpret_cast<ushort4*>(dst)[i] = o;
}

// ---------------- staging: rows x 128 bytes, XOR slot-swizzled ----------------
// 256-thread (4-wave) version: each wave stages 4KB (32 rows)
__device__ __forceinline__ void stage128_swz(const char* g, int gstride, char* lds, int tid) {
    int wave = tid >> 6, lane = tid & 63;
#pragma unroll
    for (int j = 0; j < 4; ++j) {
        int o = ((wave * 4 + j) * 64 + lane) * 16;
        int r = o >> 7;
        int slot = (o >> 4) & 7;
        const char* src = g + (size_t)r * gstride + ((slot ^ (r & 7)) << 4);
        __builtin_amdgcn_global_load_lds((const __attribute__((address_space(1))) void*)src,
                                         (__attribute__((address_space(3))) void*)(lds + (wave * 4 + j) * 1024),
                                         16, 0, 0);
    }
}
// 512-thread (8-wave) version: each wave stages 1KB (8 rows of a 64x128B tile)
__device__ __forceinline__ void stage64_swz8(const char* g, int gstride, char* lds, int tid) {
    int wave = tid >> 6, lane = tid & 63;
    int o = (wave * 64 + lane) * 16;
    int r = o >> 7;                 // wave*8 + lane>>3
    int slot = (o >> 4) & 7;        // lane&7
    const char* src = g + (size_t)r * gstride + ((slot ^ (r & 7)) << 4);
    __builtin_amdgcn_global_load_lds((const __attribute__((address_space(1))) void*)src,
                                     (__attribute__((address_space(3))) void*)(lds + wave * 1024 + lane * 16),
                                     16, 0, 0);
}

__device__ __forceinline__ bf16x8 frag_swz(const char* lds, int row, int slot) {
    return *reinterpret_cast<const bf16x8*>(lds + row * 128 + (((slot) ^ (row & 7)) << 4));
}

__device__ __forceinline__ float vmax16(const f32x16& v) {
    float a0 = fmaxf(v[0], v[1]), a1 = fmaxf(v[2], v[3]);
    float a2 = fmaxf(v[4], v[5]), a3 = fmaxf(v[6], v[7]);
    float a4 = fmaxf(v[8], v[9]), a5 = fmaxf(v[10], v[11]);
    float a6 = fmaxf(v[12], v[13]), a7 = fmaxf(v[14], v[15]);
    float b0 = fmaxf(a0, a1), b1 = fmaxf(a2, a3), b2 = fmaxf(a4, a5), b3 = fmaxf(a6, a7);
    return fmaxf(fmaxf(b0, b1), fmaxf(b2, b3));
}

// ---------------- fused QKV projection GEMM: C[M,N] = A[M,K] * W[N,K]^T ----------------
// 2D grid (64,24): per-XCD A-panel residency (row strided mod 8) + concurrent W-tile
// sharing come for free from dispatch order. (1D clustered remap regressed 55->80us, R8.)
__global__ __launch_bounds__(256) void gemm_qkv(const unsigned short* __restrict__ xb,
                                                const unsigned short* __restrict__ Wq,
                                                const unsigned short* __restrict__ Wk,
                                                const unsigned short* __restrict__ Wv,
                                                unsigned short* __restrict__ Qo,
                                                unsigned short* __restrict__ Ko,
                                                unsigned short* __restrict__ Vo) {
    __shared__ __align__(16) char As[128 * 128];
    __shared__ __align__(16) char Bs[128 * 128];
    int tid = threadIdx.x, lane = tid & 63, wave = tid >> 6;
    int wr = wave >> 1, wc = wave & 1;
    int brow = blockIdx.x * 128;
    int mat = blockIdx.y >> 3;
    int bcol = (blockIdx.y & 7) * 128;
    const unsigned short* W = mat == 0 ? Wq : (mat == 1 ? Wk : Wv);
    unsigned short* O = mat == 0 ? Qo : (mat == 1 ? Ko : Vo);
    float oscale = (mat == 0) ? QSCALE_ : 1.0f;  // fold attn scale + log2e into Q
    f32x4 acc[4][4] = {};
    const char* ga = (const char*)(xb + (size_t)brow * H_);
    const char* gb = (const char*)(W + (size_t)bcol * H_);
    int ro = lane & 15, kg = lane >> 4;
    for (int kt = 0; kt < H_ / 64; ++kt) {
        stage128_swz(ga + kt * 128, H_ * 2, As, tid);
        stage128_swz(gb + kt * 128, H_ * 2, Bs, tid);
        __syncthreads();
#pragma unroll
        for (int kk = 0; kk < 2; ++kk) {
            bf16x8 af[4], bfr[4];
#pragma unroll
            for (int m = 0; m < 4; ++m) af[m] = frag_swz(As, wr * 64 + m * 16 + ro, kk * 4 + kg);
#pragma unroll
            for (int n = 0; n < 4; ++n) bfr[n] = frag_swz(Bs, wc * 64 + n * 16 + ro, kk * 4 + kg);
#pragma unroll
            for (int m = 0; m < 4; ++m)
#pragma unroll
                for (int n = 0; n < 4; ++n)
                    acc[m][n] = __builtin_amdgcn_mfma_f32_16x16x32_bf16(af[m], bfr[n], acc[m][n], 0, 0, 0);
        }
        __syncthreads();
    }
#pragma unroll
    for (int m = 0; m < 4; ++m)
#pragma unroll
        for (int n = 0; n < 4; ++n)
#pragma unroll
            for (int i = 0; i < 4; ++i) {
                int row = brow + wr * 64 + m * 16 + kg * 4 + i;
                int col = bcol + wc * 64 + n * 16 + ro;
                O[(size_t)row * H_ + col] = f2bf(acc[m][n][i] * oscale);
            }
}

// ---------------- output projection GEMM + bias, fp32 out (2D grid) ----------------
__global__ __launch_bounds__(256) void gemm_out(const unsigned short* __restrict__ Ab,
                                                const unsigned short* __restrict__ Wo,
                                                const float* __restrict__ bo,
                                                float* __restrict__ out) {
    __shared__ __align__(16) char As[128 * 128];
    __shared__ __align__(16) char Bs[128 * 128];
    int tid = threadIdx.x, lane = tid & 63, wave = tid >> 6;
    int wr = wave >> 1, wc = wave & 1;
    int brow = blockIdx.x * 128;
    int bcol = blockIdx.y * 128;
    f32x4 acc[4][4] = {};
    const char* ga = (const char*)(Ab + (size_t)brow * H_);
    const char* gb = (const char*)(Wo + (size_t)bcol * H_);
    int ro = lane & 15, kg = lane >> 4;
    for (int kt = 0; kt < H_ / 64; ++kt) {
        stage128_swz(ga + kt * 128, H_ * 2, As, tid);
        stage128_swz(gb + kt * 128, H_ * 2, Bs, tid);
        __syncthreads();
#pragma unroll
        for (int kk = 0; kk < 2; ++kk) {
            bf16x8 af[4], bfr[4];
#pragma unroll
            for (int m = 0; m < 4; ++m) af[m] = frag_swz(As, wr * 64 + m * 16 + ro, kk * 4 + kg);
#pragma unroll
            for (int n = 0; n < 4; ++n) bfr[n] = frag_swz(Bs, wc * 64 + n * 16 + ro, kk * 4 + kg);
#pragma unroll
            for (int m = 0; m < 4; ++m)
#pragma unroll
                for (int n = 0; n < 4; ++n)
                    acc[m][n] = __builtin_amdgcn_mfma_f32_16x16x32_bf16(af[m], bfr[n], acc[m][n], 0, 0, 0);
        }
        __syncthreads();
    }
#pragma unroll
    for (int n = 0; n < 4; ++n) {
        int col = bcol + wc * 64 + n * 16 + ro;
        float bn = bo[col];
#pragma unroll
        for (int m = 0; m < 4; ++m)
#pragma unroll
            for (int i = 0; i < 4; ++i) {
                int row = brow + wr * 64 + m * 16 + kg * 4 + i;
                out[(size_t)row * H_ + col] = acc[m][n][i] + bn;
            }
    }
}

// ---------------- flash attention: 8 waves x 32 q-rows (QBLK=256), KVBLK=64 ----------------
// R7-verified two-barrier skeleton; staging split across 8 waves (half cost/wave).
// grid: 512 blocks; qb permuted so co-resident blocks' work sums are equal.
__global__ __launch_bounds__(512) void attn(const unsigned short* __restrict__ Q,
                                            const unsigned short* __restrict__ K,
                                            const unsigned short* __restrict__ V,
                                            const int* __restrict__ amask,
                                            unsigned short* __restrict__ Ab) {
    __shared__ __align__(16) char lds[32768];
    char* Ksm = lds;                                             // 16KB K dbuf
    unsigned short* Vt = (unsigned short*)(lds + 16384);         // 8KB V^T swizzled
    unsigned char* maskc = (unsigned char*)(lds + 24576);        // 2KB
    unsigned char* anyz = (unsigned char*)(lds + 26624);         // 32B
    // epilogue reuses all 32KB as O-transpose buffer

    int tid = threadIdx.x, lane = tid & 63, w = tid >> 6;        // w 0..7
    int l31 = lane & 31, hi = lane >> 5, hi4 = hi * 4;
    int id = blockIdx.x;
    int g = id >> 6;
    int qb = (g < 4) ? (7 - 2 * g) : (2 * g - 8);   // balanced pairs: qb(g)+qb(g+4)=7, heavy first
    int bh = id & 63, b = bh >> 4, h = bh & 15;
    int brow = qb * 256;
    int Qwg = brow + w * 32;          // wave's q-base; lane's q-row = Qwg + l31

    // per-lane causal bitmask for the diagonal 32x32 sub-block (kv_local > q_local)
    unsigned cm = 0;
#pragma unroll
    for (int r = 0; r < 16; ++r)
        if (((r & 3) + 8 * (r >> 2) + hi4) > l31) cm |= (1u << r);

    const unsigned short* Qg = Q + (size_t)(b * S_ + Qwg + l31) * H_ + h * HD_;
    const unsigned short* Kg = K + (size_t)b * S_ * H_ + h * HD_;
    const unsigned short* Vg = V + (size_t)b * S_ * H_ + h * HD_;

    // prologue: stage K(0); load V(0); hoist padding mask; load Q frags
    stage64_swz8((const char*)Kg, H_ * 2, Ksm, tid);
    int vr = tid & 63, vd0 = (tid >> 6) * 8;    // each thread owns (kv=vr, d=vd0..vd0+7)
    bf16x8 vreg = *reinterpret_cast<const bf16x8*>(Vg + (size_t)vr * H_ + vd0);
    {
        const int4* am4 = reinterpret_cast<const int4*>(amask + b * S_);
        int i = tid;
        if (i < S_ / 4) {
            int4 v = am4[i];
            uchar4 o;
            o.x = (v.x == 0); o.y = (v.y == 0); o.z = (v.z == 0); o.w = (v.w == 0);
            reinterpret_cast<uchar4*>(maskc)[i] = o;
        }
    }
    bf16x8 qf[4];
#pragma unroll
    for (int kk = 0; kk < 4; ++kk)
        qf[kk] = *reinterpret_cast<const bf16x8*>(Qg + kk * 16 + hi * 8);

    __syncthreads();  // prologue: K(0)/V(0) drained; maskc visible
    if (tid < 32) {   // per-64-kv "any masked" byte (covered by barrier #1 of t=0)
        const unsigned* mw = reinterpret_cast<const unsigned*>(maskc + tid * 64);
        unsigned o = 0;
#pragma unroll
        for (int i = 0; i < 16; ++i) o |= mw[i];
        anyz[tid] = o ? 1 : 0;
    }

    f32x16 oacc0, oacc1;
#pragma unroll
    for (int j = 0; j < 16; ++j) { oacc0[j] = 0.f; oacc1[j] = 0.f; }
    float mrun = -__builtin_inff(), lrun = 0.f;

    int T = 4 * qb + 4;
    for (int t = 0; t < T; ++t) {
        int kv0 = t * 64;
        const char* Kc = Ksm + (t & 1) * 8192;

        // scatter vreg (= V(t)) -> Vt, cheap factored swizzle addressing
        {
            unsigned short* vb = Vt + vd0 * 64 + (vr & 7);
            int rs3 = (vr >> 3) << 3;
#pragma unroll
            for (int j = 0; j < 8; ++j)
                vb[j * 64 + (rs3 ^ (j << 3))] = (unsigned short)vreg[j];
        }
        __syncthreads();  // #1: Vt visible; K(t) already drained (prev #2 / prologue)

        // stage K(t+1) into other buffer; prefetch V(t+1) into registers
        if (t + 1 < T)
            stage64_swz8((const char*)(Kg + (size_t)(kv0 + 64) * H_), H_ * 2,
                         Ksm + ((t + 1) & 1) * 8192, tid);
        {
            int kvn = (t + 1 < T) ? kv0 + 64 : kv0;
            vreg = *reinterpret_cast<const bf16x8*>(Vg + (size_t)(kvn + vr) * H_ + vd0);
        }

        int c0 = kv0, c1 = kv0 + 32;
        if (c0 <= Qwg) {             // wave-uniform: any visible work in this tile
            bool vis1 = (c1 <= Qwg);
            f32x16 sa0, sa1;
#pragma unroll
            for (int j = 0; j < 16; ++j) { sa0[j] = 0.f; sa1[j] = 0.f; }

            __builtin_amdgcn_s_setprio(1);
#pragma unroll
            for (int kk = 0; kk < 4; ++kk) {
                bf16x8 kf0 = frag_swz(Kc, l31, 2 * kk + hi);
                sa0 = __builtin_amdgcn_mfma_f32_32x32x16_bf16(kf0, qf[kk], sa0, 0, 0, 0);
                if (vis1) {
                    bf16x8 kf1 = frag_swz(Kc, 32 + l31, 2 * kk + hi);
                    sa1 = __builtin_amdgcn_mfma_f32_32x32x16_bf16(kf1, qf[kk], sa1, 0, 0, 0);
                }
            }
            __builtin_amdgcn_s_setprio(0);

            // causal: diagonal sub-block at most once per wave
            if (c0 == Qwg) {
#pragma unroll
                for (int r = 0; r < 16; ++r) sa0[r] = (cm & (1u << r)) ? -1e9f : sa0[r];
            }
            if (vis1 && c1 == Qwg) {
#pragma unroll
                for (int r = 0; r < 16; ++r) sa1[r] = (cm & (1u << r)) ? -1e9f : sa1[r];
            }
            // padding mask (skipped when this 64-kv group is all-ones)
            if (anyz[t]) {
#pragma unroll
                for (int u = 0; u < 4; ++u) {
                    uchar4 mk = *reinterpret_cast<const uchar4*>(maskc + kv0 + 8 * u + hi4);
                    if (mk.x) sa0[4 * u + 0] = -1e9f;
                    if (mk.y) sa0[4 * u + 1] = -1e9f;
                    if (mk.z) sa0[4 * u + 2] = -1e9f;
                    if (mk.w) sa0[4 * u + 3] = -1e9f;
                }
                if (vis1) {
#pragma unroll
                    for (int u = 0; u < 4; ++u) {
                        uchar4 mk = *reinterpret_cast<const uchar4*>(maskc + kv0 + 32 + 8 * u + hi4);
                        if (mk.x) sa1[4 * u + 0] = -1e9f;
                        if (mk.y) sa1[4 * u + 1] = -1e9f;
                        if (mk.z) sa1[4 * u + 2] = -1e9f;
                        if (mk.w) sa1[4 * u + 3] = -1e9f;
                    }
                }
            }

            // tree row-max; cross-half via shfl
            float mx = vmax16(sa0);
            if (vis1) mx = fmaxf(mx, vmax16(sa1));
            mx = fmaxf(mx, __shfl_xor(mx, 32));

            // threshold defer-rescale: only pay the O-pass when max grows by >10 (log2)
            if (__any(mx > mrun + 10.f)) {
                float mnew = fmaxf(mrun, mx);
                float fsc = exp2f_hw(mrun - mnew);
                mrun = mnew;
                lrun *= fsc;
#pragma unroll
                for (int j = 0; j < 16; ++j) { oacc0[j] *= fsc; oacc1[j] *= fsc; }
            }

            // fused per-n: exp2 -> pack bf16 -> permlane -> PV MFMA
            float rs = 0.f;
            __builtin_amdgcn_s_setprio(1);
#pragma unroll
            for (int n = 0; n < 2; ++n) {
                if (n == 1 && !vis1) break;
                const f32x16& sa = (n == 0) ? sa0 : sa1;
                unsigned int wrd[4][2];
#pragma unroll
                for (int u = 0; u < 4; ++u) {
                    float p0 = exp2f_hw(sa[4 * u + 0] - mrun);
                    float p1 = exp2f_hw(sa[4 * u + 1] - mrun);
                    float p2 = exp2f_hw(sa[4 * u + 2] - mrun);
                    float p3 = exp2f_hw(sa[4 * u + 3] - mrun);
                    rs += (p0 + p1) + (p2 + p3);
                    asm("v_cvt_pk_bf16_f32 %0, %1, %2" : "=v"(wrd[u][0]) : "v"(p0), "v"(p1));
                    asm("v_cvt_pk_bf16_f32 %0, %1, %2" : "=v"(wrd[u][1]) : "v"(p2), "v"(p3));
                }
#pragma unroll
                for (int half = 0; half < 2; ++half) {
                    int u0 = 2 * half;
                    unsigned int X0 = wrd[u0][0], Y0 = wrd[u0 + 1][0];
                    unsigned int X1 = wrd[u0][1], Y1 = wrd[u0 + 1][1];
                    asm("v_permlane32_swap_b32 %0, %1" : "+v"(X0), "+v"(Y0));
                    asm("v_permlane32_swap_b32 %0, %1" : "+v"(X1), "+v"(Y1));
                    union { unsigned int u[4]; bf16x8 v; } bu;
                    bu.u[0] = X0; bu.u[1] = X1; bu.u[2] = Y0; bu.u[3] = Y1;
                    int kc = 2 * n + half;
                    bf16x8 af0 = *reinterpret_cast<const bf16x8*>(
                        &Vt[(l31) * 64 + (((2 * kc + hi) ^ (l31 & 7)) << 3)]);
                    oacc0 = __builtin_amdgcn_mfma_f32_32x32x16_bf16(af0, bu.v, oacc0, 0, 0, 0);
                    bf16x8 af1 = *reinterpret_cast<const bf16x8*>(
                        &Vt[(32 + l31) * 64 + (((2 * kc + hi) ^ (l31 & 7)) << 3)]);
                    oacc1 = __builtin_amdgcn_mfma_f32_32x32x16_bf16(af1, bu.v, oacc1, 0, 0, 0);
                }
            }
            __builtin_amdgcn_s_setprio(0);

            rs += __shfl_xor(rs, 32);
            lrun += rs;
        }
        __syncthreads();  // #2: Vt reads done; K(t+1)/V(t+1) prefetch drained
    }

    // epilogue: divide by row sum, transpose O^T -> O via LDS (reuse all 32KB), store
    float inv = 1.f / lrun;
    unsigned short* Osm = reinterpret_cast<unsigned short*>(lds);
#pragma unroll
    for (int r = 0; r < 16; ++r) {
        int d = (r & 3) + 8 * (r >> 2) + hi4;
        Osm[w * 2048 + l31 * 64 + ((((d >> 3) ^ (l31 & 7)) << 3) | (d & 7))] = f2bf(oacc0[r] * inv);
        int d1 = d + 32;
        Osm[w * 2048 + l31 * 64 + ((((d1 >> 3) ^ (l31 & 7)) << 3) | (d1 & 7))] = f2bf(oacc1[r] * inv);
    }
    __syncthreads();
#pragma unroll
    for (int wv = 0; wv < 4; ++wv) {
        int q = tid >> 3, j = tid & 7;      // q 0..63
        int row = wv * 64 + q;              // 0..255
        bf16x8 vv = *reinterpret_cast<const bf16x8*>(
            Osm + (row >> 5) * 2048 + (row & 31) * 64 + ((j ^ (row & 7)) << 3));
        size_t grow = (size_t)(b * S_ + brow + row);
        *reinterpret_cast<bf16x8*>(Ab + grow * H_ + h * HD_ + j * 8) = vv;
    }
}

extern "C" void kernel_launch(void* const* d_in, const int* in_sizes, int n_in,
                              void* d_out, int out_size, void* d_ws, size_t ws_size,
                              hipStream_t stream) {
    const float* x  = (const float*)d_in[0];
    const int* amask = (const int*)d_in[1];
    const float* Wq = (const float*)d_in[2];
    const float* Wk = (const float*)d_in[3];
    const float* Wv = (const float*)d_in[4];
    const float* Wo = (const float*)d_in[5];
    const float* bo = (const float*)d_in[6];
    float* out = (float*)d_out;

    const size_t XN = (size_t)B_ * S_ * H_;   // 8388608
    const size_t WN = (size_t)H_ * H_;        // 1048576

    char* ws = (char*)d_ws;
    unsigned short* xb  = (unsigned short*)ws;           ws += XN * 2;
    unsigned short* Wqb = (unsigned short*)ws;           ws += WN * 2;
    unsigned short* Wkb = (unsigned short*)ws;           ws += WN * 2;
    unsigned short* Wvb = (unsigned short*)ws;           ws += WN * 2;
    unsigned short* Wob = (unsigned short*)ws;           ws += WN * 2;
    unsigned short* Qb  = (unsigned short*)ws;           ws += XN * 2;
    unsigned short* Kb  = (unsigned short*)ws;           ws += XN * 2;
    unsigned short* Vb  = (unsigned short*)ws;           ws += XN * 2;
    unsigned short* Ab  = (unsigned short*)ws;           ws += XN * 2;

    cast_all<<<12288, 256, 0, stream>>>(x, Wq, Wk, Wv, Wo, xb, Wqb, Wkb, Wvb, Wob);
    gemm_qkv<<<dim3(64, 24), 256, 0, stream>>>(xb, Wqb, Wkb, Wvb, Qb, Kb, Vb);
    attn<<<512, 512, 0, stream>>>(Qb, Kb, Vb, amask, Ab);
    gemm_out<<<dim3(64, 8), 256, 0, stream>>>(Ab, Wob, bo, out);
}